// Round 3
// baseline (2662.828 us; speedup 1.0000x reference)
//
#include <hip/hip_runtime.h>

// ---------------------------------------------------------------------------
// ConvBERT layer forward, bf16 compute / fp32 accumulate.
// B=8 S=1024 H=1536 NH=8 HD=96 AH=768 K=7 IM=3072
// Round 2: dtype-adaptive input reads (bf16 vs fp32 probed on device),
//          arena tightened to ~143 MB, FFN split into 2 K-chunks w/ beta-GEMM.
// ---------------------------------------------------------------------------

typedef __bf16 bf16_t;
typedef short s16x8 __attribute__((ext_vector_type(8)));   // 8 bf16 in 4 VGPRs
typedef float f32x4 __attribute__((ext_vector_type(4)));

#define BB  8
#define SS  1024
#define HH  1536
#define NHH 8
#define HDD 96
#define AHH 768
#define IMM 3072

__device__ __forceinline__ float rd_adapt(const void* p, long long i, int isbf) {
    return isbf ? (float)((const bf16_t*)p)[i] : ((const float*)p)[i];
}

// ---------------------------------------------------------------------------
// dtype probe: read first 256 elements of embed as bf16; if the data is really
// fp32, even-index decodes are mantissa garbage (~53% sane overall) vs ~100%
// sane for true bf16 N(0,1) data. flag=1 -> bf16 inputs, flag=0 -> fp32.
// ---------------------------------------------------------------------------
__global__ __launch_bounds__(256)
void detect_kernel(const void* __restrict__ embed, int* __restrict__ flag)
{
    __shared__ int cnt[256];
    int t = threadIdx.x;
    float x = (float)((const bf16_t*)embed)[t];
    float a = fabsf(x);
    cnt[t] = (a > 1e-3f && a < 50.0f) ? 1 : 0;   // NaN compares false -> 0
    __syncthreads();
    for (int o = 128; o > 0; o >>= 1) { if (t < o) cnt[t] += cnt[t + o]; __syncthreads(); }
    if (t == 0) *flag = (cnt[0] >= 205) ? 1 : 0;
}

// embed -> bf16 copy (grid covers 8192*1536 elements, 8 per thread)
__global__ __launch_bounds__(256)
void convert_embed(const void* __restrict__ in, bf16_t* __restrict__ out,
                   const int* __restrict__ flagp)
{
    int isbf = *flagp;
    long long i0 = ((long long)blockIdx.x * 256 + threadIdx.x) * 8;
    if (isbf) {
        *(s16x8*)(out + i0) = *(const s16x8*)((const bf16_t*)in + i0);
    } else {
        const float* f = (const float*)in;
        #pragma unroll
        for (int j = 0; j < 8; j++) out[i0 + j] = (bf16_t)f[i0 + j];
    }
}

// ---------------------------------------------------------------------------
// Generic batched GEMM: C[m,n] = post( scale*sum_k A[m,k]*Bt[n,k] + bias + bC )
// A: bf16 [M,Kd] (lda); Bt: bf16 [Npad16,Kd] (ldb).  bias is adaptive-dtype.
// beta=1 adds existing C. emul: elementwise multiply. act=1: exact GELU.
// ---------------------------------------------------------------------------
__global__ __launch_bounds__(256)
void gemm_bt(const bf16_t* __restrict__ A, const bf16_t* __restrict__ Bt,
             bf16_t* __restrict__ C, const void* __restrict__ bias, long long biasOff,
             const bf16_t* __restrict__ emul, const int* __restrict__ flagp,
             int M, int N, int Kd, int lda, int ldb, int ldc,
             long long sAb, long long sAh, long long sBb, long long sBh,
             long long sCb, long long sCh, int nh, float scale, int act, int beta)
{
    int isbf = flagp ? *flagp : 1;
    int z  = blockIdx.z;
    int zb = z / nh, zh = z - zb * nh;
    const bf16_t* Ap = A  + zb * sAb + zh * sAh;
    const bf16_t* Bp = Bt + zb * sBb + zh * sBh;
    bf16_t*       Cp = C  + zb * sCb + zh * sCh;
    const bf16_t* Ep = emul ? (emul + zb * sCb + zh * sCh) : (const bf16_t*)nullptr;

    int tid  = threadIdx.x;
    int wave = tid >> 6, lane = tid & 63;
    int wm = wave >> 1, wn = wave & 1;
    int row0 = blockIdx.x * 128 + wm * 64;
    int col0 = blockIdx.y * 64  + wn * 32;
    int lm = lane & 15;      // A row / B col / C col within 16-tile
    int kq = lane >> 4;      // 0..3 : k-quad

    bool nv0 = (col0)      < N;
    bool nv1 = (col0 + 16) < N;

    f32x4 acc[4][2] = {};

    const bf16_t* arow  = Ap + (long long)(row0 + lm) * lda + kq * 8;
    const bf16_t* brow0 = Bp + (long long)(col0 + lm) * ldb + kq * 8;
    const bf16_t* brow1 = Bp + (long long)(col0 + 16 + lm) * ldb + kq * 8;

    for (int k0 = 0; k0 < Kd; k0 += 32) {
        s16x8 a0 = *(const s16x8*)(arow + k0);
        s16x8 a1 = *(const s16x8*)(arow + k0 + 16ll * lda);
        s16x8 a2 = *(const s16x8*)(arow + k0 + 32ll * lda);
        s16x8 a3 = *(const s16x8*)(arow + k0 + 48ll * lda);
        s16x8 b0 = {}; if (nv0) b0 = *(const s16x8*)(brow0 + k0);
        s16x8 b1 = {}; if (nv1) b1 = *(const s16x8*)(brow1 + k0);
        acc[0][0] = __builtin_amdgcn_mfma_f32_16x16x32_bf16(a0, b0, acc[0][0], 0, 0, 0);
        acc[1][0] = __builtin_amdgcn_mfma_f32_16x16x32_bf16(a1, b0, acc[1][0], 0, 0, 0);
        acc[2][0] = __builtin_amdgcn_mfma_f32_16x16x32_bf16(a2, b0, acc[2][0], 0, 0, 0);
        acc[3][0] = __builtin_amdgcn_mfma_f32_16x16x32_bf16(a3, b0, acc[3][0], 0, 0, 0);
        acc[0][1] = __builtin_amdgcn_mfma_f32_16x16x32_bf16(a0, b1, acc[0][1], 0, 0, 0);
        acc[1][1] = __builtin_amdgcn_mfma_f32_16x16x32_bf16(a1, b1, acc[1][1], 0, 0, 0);
        acc[2][1] = __builtin_amdgcn_mfma_f32_16x16x32_bf16(a2, b1, acc[2][1], 0, 0, 0);
        acc[3][1] = __builtin_amdgcn_mfma_f32_16x16x32_bf16(a3, b1, acc[3][1], 0, 0, 0);
    }

    // epilogue: C/D layout row = kq*4 + r, col = lm  (m89/m91-verified)
    #pragma unroll
    for (int j = 0; j < 2; j++) {
        int gcol = col0 + j * 16 + lm;
        if (gcol >= N) continue;
        float bv = bias ? rd_adapt(bias, biasOff + gcol, isbf) : 0.0f;
        #pragma unroll
        for (int i = 0; i < 4; i++) {
            int grow0 = row0 + i * 16 + kq * 4;
            #pragma unroll
            for (int r = 0; r < 4; r++) {
                float v = acc[i][j][r] * scale + bv;
                long long ci = (long long)(grow0 + r) * ldc + gcol;
                if (beta) v += (float)Cp[ci];
                if (Ep) v *= (float)Ep[ci];
                if (act) v = 0.5f * v * (1.0f + erff(v * 0.70710678118654752f));
                Cp[ci] = (bf16_t)v;
            }
        }
    }
}

// ---------------------------------------------------------------------------
// Adaptive tiled transpose with zero-padding beyond C columns.
// in (elem offset inOff + z*sInB): [R x C] with row-stride ldin.
// out: [Cpad x R] bf16 (+ z*sOutB), Cpad = gridDim.x*32.
// flagp==nullptr means input is internal bf16.
// ---------------------------------------------------------------------------
__global__ __launch_bounds__(256)
void transpose_pad(const void* __restrict__ in, bf16_t* __restrict__ out,
                   int R, int C, int ldin, long long inOff,
                   long long sInB, long long sOutB, const int* __restrict__ flagp)
{
    __shared__ bf16_t t[32][33];
    int isbf = flagp ? *flagp : 1;
    int z = blockIdx.z;
    long long base = inOff + (long long)z * sInB;
    bf16_t* op = out + (long long)z * sOutB;
    int tx = threadIdx.x & 31, ty = threadIdx.x >> 5;
    int cb = blockIdx.x * 32, rb = blockIdx.y * 32;
    #pragma unroll
    for (int rr = ty; rr < 32; rr += 8) {
        int r = rb + rr, c = cb + tx;
        t[rr][tx] = (c < C) ? (bf16_t)rd_adapt(in, base + (long long)r * ldin + c, isbf)
                            : (bf16_t)0.0f;
    }
    __syncthreads();
    #pragma unroll
    for (int rr = ty; rr < 32; rr += 8) {
        int c = cb + rr;
        op[(long long)c * R + rb + tx] = t[tx][rr];
    }
}

// depthwise conv k=7, 'same' padding along S; ebuf is internal bf16, dw adaptive
__global__ __launch_bounds__(256)
void dconv_kernel(const bf16_t* __restrict__ ebuf, const void* __restrict__ dw,
                  bf16_t* __restrict__ out, const int* __restrict__ flagp)
{
    int isbf = *flagp;
    long long i = (long long)blockIdx.x * 256 + threadIdx.x;   // < B*S*H
    int c = (int)(i % HH);
    long long bs = i / HH;
    int s = (int)(bs % SS);
    float acc = 0.0f;
    #pragma unroll
    for (int k = 0; k < 7; k++) {
        int ss = s + k - 3;
        if (ss >= 0 && ss < SS)
            acc += (float)ebuf[(bs + (k - 3)) * HH + c] * rd_adapt(dw, c * 7 + k, isbf);
    }
    out[i] = (bf16_t)acc;
}

// ck softmax over k=7 per (b,s,h); input bf16 [B*S,64], output fp32 [B*S,56]
__global__ __launch_bounds__(256)
void ck_softmax(const bf16_t* __restrict__ ck, float* __restrict__ ckp)
{
    int i = blockIdx.x * 256 + threadIdx.x;   // < B*S*NH
    if (i >= BB * SS * NHH) return;
    int h = i % NHH;
    long long bs = i / NHH;
    const bf16_t* src = ck + bs * 64 + h * 7;
    float v[7], mx = -1e30f;
    #pragma unroll
    for (int k = 0; k < 7; k++) { v[k] = (float)src[k]; mx = fmaxf(mx, v[k]); }
    float sum = 0.0f;
    #pragma unroll
    for (int k = 0; k < 7; k++) { v[k] = expf(v[k] - mx); sum += v[k]; }
    float inv = 1.0f / sum;
    float* dst = ckp + bs * 56 + h * 7;
    #pragma unroll
    for (int k = 0; k < 7; k++) dst[k] = v[k] * inv;
}

// conv_out -> right half (cols 768..1535) of ctxcat [B*S,1536]
__global__ __launch_bounds__(256)
void conv_out_kernel(const bf16_t* __restrict__ co, const float* __restrict__ ckp,
                     bf16_t* __restrict__ ctxcat)
{
    long long i = (long long)blockIdx.x * 256 + threadIdx.x;   // < B*S*AH
    int hd = (int)(i % AHH);
    long long bs = i / AHH;
    int s = (int)(bs % SS);
    int h = hd / HDD;
    const float* w = ckp + bs * 56 + h * 7;
    float acc = 0.0f;
    #pragma unroll
    for (int k = 0; k < 7; k++) {
        int ss = s + k - 3;
        if (ss >= 0 && ss < SS)
            acc += (float)co[(bs + (k - 3)) * AHH + hd] * w[k];
    }
    ctxcat[bs * HH + AHH + hd] = (bf16_t)acc;
}

// row softmax, L=1024, in-place bf16, fp32 math
__global__ __launch_bounds__(256)
void softmax_rows(bf16_t* __restrict__ p)
{
    long long row = blockIdx.x;
    bf16_t* x = p + row * 1024;
    int tid = threadIdx.x;
    float v[4], mx = -1e30f;
    #pragma unroll
    for (int i = 0; i < 4; i++) { v[i] = (float)x[tid + i * 256]; mx = fmaxf(mx, v[i]); }
    __shared__ float sm[256];
    sm[tid] = mx; __syncthreads();
    for (int o = 128; o > 0; o >>= 1) { if (tid < o) sm[tid] = fmaxf(sm[tid], sm[tid + o]); __syncthreads(); }
    mx = sm[0]; __syncthreads();
    float sum = 0.0f;
    #pragma unroll
    for (int i = 0; i < 4; i++) { v[i] = expf(v[i] - mx); sum += v[i]; }
    sm[tid] = sum; __syncthreads();
    for (int o = 128; o > 0; o >>= 1) { if (tid < o) sm[tid] += sm[tid + o]; __syncthreads(); }
    float inv = 1.0f / sm[0];
    #pragma unroll
    for (int i = 0; i < 4; i++) x[tid + i * 256] = (bf16_t)(v[i] * inv);
}

// LayerNorm over 1536 of (y + res); g/bta adaptive-dtype; bf16 output
__global__ __launch_bounds__(256)
void ln_kernel(const bf16_t* __restrict__ y, const bf16_t* __restrict__ res,
               const void* __restrict__ g, const void* __restrict__ bta,
               bf16_t* __restrict__ outb, const int* __restrict__ flagp)
{
    int isbf = *flagp;
    long long row = blockIdx.x;
    const bf16_t* yp = y + row * HH;
    const bf16_t* rp = res + row * HH;
    int tid = threadIdx.x;
    float x[6], s = 0.0f, s2 = 0.0f;
    #pragma unroll
    for (int i = 0; i < 6; i++) {
        int c = tid + i * 256;
        float v = (float)yp[c] + (float)rp[c];
        x[i] = v; s += v; s2 += v * v;
    }
    __shared__ float sa[256], sb[256];
    sa[tid] = s; sb[tid] = s2; __syncthreads();
    for (int o = 128; o > 0; o >>= 1) {
        if (tid < o) { sa[tid] += sa[tid + o]; sb[tid] += sb[tid + o]; }
        __syncthreads();
    }
    float mean = sa[0] * (1.0f / HH);
    float var  = sb[0] * (1.0f / HH) - mean * mean;
    float inv  = rsqrtf(var + 1e-12f);
    #pragma unroll
    for (int i = 0; i < 6; i++) {
        int c = tid + i * 256;
        float v = (x[i] - mean) * inv * rd_adapt(g, c, isbf) + rd_adapt(bta, c, isbf);
        outb[row * HH + c] = (bf16_t)v;
    }
}

// pooled[b,c] = max_s lout[b,s,c]  (bf16 in, fp32 out)
__global__ __launch_bounds__(256)
void maxpool_kernel(const bf16_t* __restrict__ lo, float* __restrict__ pooled)
{
    int i = blockIdx.x * 256 + threadIdx.x;   // < B*H
    if (i >= BB * HH) return;
    int b = i / HH, c = i % HH;
    const bf16_t* p = lo + (long long)b * SS * HH + c;
    float m = -1e30f;
    for (int s = 0; s < SS; s++) m = fmaxf(m, (float)p[(long long)s * HH]);
    pooled[i] = m;
}

// logits[b] = pooled[b,:] . wd + bd ; output dtype follows input flavor
__global__ __launch_bounds__(256)
void decoder_kernel(const float* __restrict__ pooled, const void* __restrict__ wd,
                    const void* __restrict__ bd, void* __restrict__ out,
                    const int* __restrict__ flagp)
{
    int isbf = *flagp;
    int b = blockIdx.x;
    int tid = threadIdx.x;
    float s = 0.0f;
    #pragma unroll
    for (int i = 0; i < 6; i++) {
        int c = tid + i * 256;
        s += pooled[b * HH + c] * rd_adapt(wd, c, isbf);
    }
    __shared__ float sa[256];
    sa[tid] = s; __syncthreads();
    for (int o = 128; o > 0; o >>= 1) { if (tid < o) sa[tid] += sa[tid + o]; __syncthreads(); }
    if (tid == 0) {
        float r = sa[0] + rd_adapt(bd, 0, isbf);
        if (isbf) ((bf16_t*)out)[b] = (bf16_t)r;
        else      ((float*)out)[b]  = r;
    }
}

// ---------------------------------------------------------------------------
extern "C" void kernel_launch(void* const* d_in, const int* in_sizes, int n_in,
                              void* d_out, int out_size, void* d_ws, size_t ws_size,
                              hipStream_t stream)
{
    const void* embed = d_in[0];
    const void* wq  = d_in[1];  const void* bq  = d_in[2];
    const void* wk  = d_in[3];  const void* bk  = d_in[4];
    const void* wv  = d_in[5];  const void* bv  = d_in[6];
    const void* dw  = d_in[7];  const void* pw  = d_in[8];  const void* sep_b = d_in[9];
    const void* wck = d_in[10]; const void* bck = d_in[11];
    const void* wco = d_in[12]; const void* bco = d_in[13];
    const void* wso = d_in[14]; const void* bso = d_in[15];
    const void* ln1g = d_in[16]; const void* ln1b = d_in[17];
    const void* wi  = d_in[18]; const void* bi  = d_in[19];
    const void* wo  = d_in[20]; const void* bo  = d_in[21];
    const void* ln2g = d_in[22]; const void* ln2b = d_in[23];
    const void* wd  = d_in[24]; const void* bd  = d_in[25];
    (void)ws_size; (void)in_sizes; (void)n_in; (void)out_size;

    // ---- arena (~143.2 MB), lifetime-aliased ----
    char* ws = (char*)d_ws;
    char* X0 = ws;                          // 25.17 MB: qb,kbuf -> (dead after attn)
    char* X1 = ws + 25165824;               // 37.75 MB: dconvb/sepb -> ckb/ckp -> scores -> ybuf -> inter_c -> lout
    char* X2 = ws + 62914560;               // 25.17 MB: vbuf + (cob -> vT)
    char* X4 = ws + 88080384;               // 25.17 MB: ctxcat -> attn
    char* X5 = ws + 113246208;              // 25.17 MB: ebuf -> y2
    char* XW = ws + 138412032;              //  4.72 MB: wT (max 1536x1536 bf16)
    char* XP = ws + 143130624;              //  flag + pooled

    bf16_t* qb     = (bf16_t*)X0;                   // [8192,768]
    bf16_t* kbuf   = (bf16_t*)(X0 + 12582912);      // [8192,768]
    bf16_t* dconvb = (bf16_t*)X1;                   // [8192,1536]
    bf16_t* sepb   = (bf16_t*)(X1 + 25165824);      // [8192,768]
    bf16_t* ckb    = (bf16_t*)X1;                   // [8192,64]   (after dconvb dies)
    float*  ckp    = (float*) (X1 + 1310720);       // [8192,56] f32
    bf16_t* scores = (bf16_t*)X1;                   // [64,128,1024] (16.8 MB)
    bf16_t* ybuf   = (bf16_t*)X1;                   // [8192,1536]
    bf16_t* interb = (bf16_t*)X1;                   // [8192,1536] per FFN chunk
    bf16_t* lout   = (bf16_t*)X1;                   // [8192,1536]
    bf16_t* vbuf   = (bf16_t*)X2;                   // [8192,768]
    bf16_t* cob    = (bf16_t*)(X2 + 12582912);      // [8192,768]  (dies at conv_out)
    bf16_t* vT     = (bf16_t*)(X2 + 12582912);      // [8,768,1024] (born after cob dies)
    bf16_t* ctxcat = (bf16_t*)X4;                   // [8192,1536]
    bf16_t* attn   = (bf16_t*)X4;                   // [8192,1536] (after ctxcat dies)
    bf16_t* ebuf   = (bf16_t*)X5;                   // [8192,1536] bf16 copy of embed
    bf16_t* y2     = (bf16_t*)X5;                   // [8192,1536] (after ebuf dies)
    bf16_t* wT     = (bf16_t*)XW;
    int*    flag   = (int*)XP;
    float*  pooled = (float*)(XP + 256);            // [8,1536] f32

    dim3 blk(256);

    auto gemm = [&](const bf16_t* A, const bf16_t* Bt, bf16_t* C, const void* bias,
                    long long biasOff, const bf16_t* emul,
                    int M, int N, int Kd, int lda, int ldb, int ldc,
                    long long sAb, long long sAh, long long sBb, long long sBh,
                    long long sCb, long long sCh, int nb, int nh,
                    float scale, int act, int beta) {
        dim3 g(M / 128, (N + 63) / 64, nb * nh);
        gemm_bt<<<g, blk, 0, stream>>>(A, Bt, C, bias, biasOff, emul, flag,
                                       M, N, Kd, lda, ldb, ldc,
                                       sAb, sAh, sBb, sBh, sCb, sCh, nh, scale, act, beta);
    };
    auto transpose = [&](const void* in, bf16_t* out, int R, int C, int Cpad, int ldin,
                         long long inOff, int batch, long long sInB, long long sOutB,
                         const int* fl) {
        dim3 g(Cpad / 32, R / 32, batch);
        transpose_pad<<<g, blk, 0, stream>>>(in, out, R, C, ldin, inOff, sInB, sOutB, fl);
    };

    // --- dtype probe + embed conversion ---
    detect_kernel<<<dim3(1), blk, 0, stream>>>(embed, flag);
    convert_embed<<<dim3(6144), blk, 0, stream>>>(embed, ebuf, flag);

    // --- projections ---
    transpose(wq, wT, 1536, 768, 768, 768, 0, 1, 0, 0, flag);
    gemm(ebuf, wT, qb,   bq, 0, nullptr, 8192, 768, 1536, HH, HH, AHH, 0,0,0,0,0,0, 1,1, 1.0f, 0, 0);
    transpose(wk, wT, 1536, 768, 768, 768, 0, 1, 0, 0, flag);
    gemm(ebuf, wT, kbuf, bk, 0, nullptr, 8192, 768, 1536, HH, HH, AHH, 0,0,0,0,0,0, 1,1, 1.0f, 0, 0);
    transpose(wv, wT, 1536, 768, 768, 768, 0, 1, 0, 0, flag);
    gemm(ebuf, wT, vbuf, bv, 0, nullptr, 8192, 768, 1536, HH, HH, AHH, 0,0,0,0,0,0, 1,1, 1.0f, 0, 0);
    transpose(wco, wT, 1536, 768, 768, 768, 0, 1, 0, 0, flag);
    gemm(ebuf, wT, cob, bco, 0, nullptr, 8192, 768, 1536, HH, HH, AHH, 0,0,0,0,0,0, 1,1, 1.0f, 0, 0);

    // --- separable conv: depthwise, then pointwise fused with *q ---
    dconv_kernel<<<dim3((BB * SS * HH) / 256), blk, 0, stream>>>(ebuf, dw, dconvb, flag);
    transpose(pw, wT, 1536, 768, 768, 768, 0, 1, 0, 0, flag);
    gemm(dconvb, wT, sepb, sep_b, 0, qb, 8192, 768, 1536, HH, HH, AHH, 0,0,0,0,0,0, 1,1, 1.0f, 0, 0);

    // --- span conv kernels ---
    transpose(wck, wT, 768, 56, 64, 56, 0, 1, 0, 0, flag);
    gemm(sepb, wT, ckb, bck, 0, nullptr, 8192, 56, 768, AHH, AHH, 64, 0,0,0,0,0,0, 1,1, 1.0f, 0, 0);
    ck_softmax<<<dim3((BB * SS * NHH) / 256), blk, 0, stream>>>(ckb, ckp);
    conv_out_kernel<<<dim3((BB * SS * AHH) / 256), blk, 0, stream>>>(cob, ckp, ctxcat);

    // --- attention (8 q-chunks of 128 rows; scores = 16.8 MB in X1) ---
    transpose(vbuf, vT, 1024, 768, 768, 768, 0, 8, 1024ll * 768, 768ll * 1024, nullptr);
    const float ascale = 0.1020620726159658f;   // 1/sqrt(96)
    for (int ch = 0; ch < 8; ch++) {
        const bf16_t* qc = qb + (long long)ch * 128 * AHH;
        gemm(qc, kbuf, scores, nullptr, 0, nullptr, 128, 1024, 96,
             AHH, AHH, 1024,
             (long long)SS * AHH, 96,
             (long long)SS * AHH, 96,
             8ll * 128 * 1024, 128ll * 1024,
             BB, NHH, ascale, 0, 0);
        softmax_rows<<<dim3(64 * 128), blk, 0, stream>>>(scores);
        gemm(scores, vT, ctxcat + (long long)ch * 128 * HH, nullptr, 0, nullptr,
             128, 96, 1024,
             1024, 1024, HH,
             8ll * 128 * 1024, 128ll * 1024,
             768ll * 1024, 96ll * 1024,
             (long long)SS * HH, 96,
             BB, NHH, 1.0f, 0, 0);
    }

    // --- self output + LN1 ---
    transpose(wso, wT, 1536, 1536, 1536, 1536, 0, 1, 0, 0, flag);
    gemm(ctxcat, wT, ybuf, bso, 0, nullptr, 8192, 1536, 1536, HH, HH, HH, 0,0,0,0,0,0, 1,1, 1.0f, 0, 0);
    ln_kernel<<<dim3(8192), blk, 0, stream>>>(ybuf, ebuf, ln1g, ln1b, attn, flag);

    // --- FFN in 2 chunks of IM=1536 (keeps interb at 25 MB) + LN2 ---
    for (int c = 0; c < 2; c++) {
        // wi column slice [c*1536, (c+1)*1536): [1536 x 1536] with row-stride 3072
        transpose(wi, wT, 1536, 1536, 1536, 3072, (long long)c * 1536, 1, 0, 0, flag);
        gemm(attn, wT, interb, bi, (long long)c * 1536, nullptr,
             8192, 1536, 1536, HH, 1536, 1536, 0,0,0,0,0,0, 1,1, 1.0f, 1, 0);
        // wo row slice [c*1536, (c+1)*1536): [1536 x 1536] row-stride 1536
        transpose(wo, wT, 1536, 1536, 1536, 1536, (long long)c * 1536 * 1536, 1, 0, 0, flag);
        gemm(interb, wT, y2, (c == 0 ? bo : nullptr), 0, nullptr,
             8192, 1536, 1536, 1536, 1536, HH, 0,0,0,0,0,0, 1,1, 1.0f, 0, (c == 0 ? 0 : 1));
    }
    ln_kernel<<<dim3(8192), blk, 0, stream>>>(y2, attn, ln2g, ln2b, lout, flag);

    // --- pool + decode ---
    maxpool_kernel<<<dim3((BB * HH + 255) / 256), blk, 0, stream>>>(lout, pooled);
    decoder_kernel<<<dim3(BB), blk, 0, stream>>>(pooled, wd, bd, d_out, flag);
}

// Round 4
// 1434.446 us; speedup vs baseline: 1.8563x; 1.8563x over previous
//
#include <hip/hip_runtime.h>

// ---------------------------------------------------------------------------
// ConvBERT layer forward, bf16 compute / fp32 accumulate.
// B=8 S=1024 H=1536 NH=8 HD=96 AH=768 K=7 IM=3072
// Round 4: m97-style LDS-staged 128x128 GEMM (global_load_lds width=16,
//          BK=32, 4x4 16x16x32 MFMA per wave). Attention chunks 256 rows.
// ---------------------------------------------------------------------------

typedef __bf16 bf16_t;
typedef short s16x8 __attribute__((ext_vector_type(8)));   // 8 bf16 in 4 VGPRs
typedef float f32x4 __attribute__((ext_vector_type(4)));

#define BB  8
#define SS  1024
#define HH  1536
#define NHH 8
#define HDD 96
#define AHH 768
#define IMM 3072

__device__ __forceinline__ float rd_adapt(const void* p, long long i, int isbf) {
    return isbf ? (float)((const bf16_t*)p)[i] : ((const float*)p)[i];
}

// async global->LDS, 16B per lane; lds base must be wave-uniform
__device__ __forceinline__ void gl2lds16(const bf16_t* g, bf16_t* l) {
    __builtin_amdgcn_global_load_lds(
        (__attribute__((address_space(1))) const void*)g,
        (__attribute__((address_space(3))) void*)l, 16, 0, 0);
}

// ---------------------------------------------------------------------------
// dtype probe: bf16 vs fp32 inputs (see round-2 notes). flag=1 -> bf16.
// ---------------------------------------------------------------------------
__global__ __launch_bounds__(256)
void detect_kernel(const void* __restrict__ embed, int* __restrict__ flag)
{
    __shared__ int cnt[256];
    int t = threadIdx.x;
    float x = (float)((const bf16_t*)embed)[t];
    float a = fabsf(x);
    cnt[t] = (a > 1e-3f && a < 50.0f) ? 1 : 0;
    __syncthreads();
    for (int o = 128; o > 0; o >>= 1) { if (t < o) cnt[t] += cnt[t + o]; __syncthreads(); }
    if (t == 0) *flag = (cnt[0] >= 205) ? 1 : 0;
}

__global__ __launch_bounds__(256)
void convert_embed(const void* __restrict__ in, bf16_t* __restrict__ out,
                   const int* __restrict__ flagp)
{
    int isbf = *flagp;
    long long i0 = ((long long)blockIdx.x * 256 + threadIdx.x) * 8;
    if (isbf) {
        *(s16x8*)(out + i0) = *(const s16x8*)((const bf16_t*)in + i0);
    } else {
        const float* f = (const float*)in;
        #pragma unroll
        for (int j = 0; j < 8; j++) out[i0 + j] = (bf16_t)f[i0 + j];
    }
}

// ---------------------------------------------------------------------------
// LDS-staged batched GEMM: C[m,n] = post(scale*sum_k A[m,k]*Bt[n,k] + bias +bC)
// 128x128 tile, BK=32, block=256 (4 waves), wave = 64x64 = 4x4 mfma 16x16x32.
// Staging: global_load_lds dwordx4, 2 issues per 128x32 tile.
// Requires M%128==0, Kd%32==0. B-tile row staging clamped to nlim (so N may be
// < tile width if Bt rows beyond are readable-or-clamped; epilogue guards N).
// ---------------------------------------------------------------------------
__global__ __launch_bounds__(256)
void gemm_tile(const bf16_t* __restrict__ A, const bf16_t* __restrict__ Bt,
               bf16_t* __restrict__ C, const void* __restrict__ bias, long long biasOff,
               const bf16_t* __restrict__ emul, const int* __restrict__ flagp,
               int M, int N, int Kd, int lda, int ldb, int ldc,
               long long sAb, long long sAh, long long sBb, long long sBh,
               long long sCb, long long sCh, int nh, float scale, int act, int beta,
               int nlim)
{
    __shared__ bf16_t As[128 * 32];
    __shared__ bf16_t Bs[128 * 32];

    int isbf = flagp ? *flagp : 1;
    int z  = blockIdx.z;
    int zb = z / nh, zh = z - zb * nh;
    const bf16_t* Ap = A  + zb * sAb + zh * sAh;
    const bf16_t* Bp = Bt + zb * sBb + zh * sBh;
    bf16_t*       Cp = C  + zb * sCb + zh * sCh;
    const bf16_t* Ep = emul ? (emul + zb * sCb + zh * sCh) : (const bf16_t*)nullptr;

    int tid  = threadIdx.x;
    int wave = tid >> 6, lane = tid & 63;
    int wm = wave >> 1, wn = wave & 1;
    int row0 = blockIdx.x * 128;
    int col0 = blockIdx.y * 128;
    int lm = lane & 15;      // row within 16-tile
    int kq = lane >> 4;      // 0..3

    // staging: thread t covers elements t*8..t*8+7 of the row-major 128x32 tile
    int sr = tid >> 2;            // 0..63 (+64 on second issue)
    int sc = (tid & 3) * 8;       // 0,8,16,24
    const bf16_t* ga0 = Ap + (long long)(row0 + sr) * lda + sc;
    const bf16_t* ga1 = Ap + (long long)(row0 + 64 + sr) * lda + sc;
    int br0 = min(col0 + sr, nlim);
    int br1 = min(col0 + 64 + sr, nlim);
    const bf16_t* gb0 = Bp + (long long)br0 * ldb + sc;
    const bf16_t* gb1 = Bp + (long long)br1 * ldb + sc;
    bf16_t* la0 = As + wave * 512;            // wave-uniform LDS bases
    bf16_t* la1 = As + 2048 + wave * 512;
    bf16_t* lb0 = Bs + wave * 512;
    bf16_t* lb1 = Bs + 2048 + wave * 512;

    f32x4 acc[4][4] = {};

    for (int k0 = 0; k0 < Kd; k0 += 32) {
        gl2lds16(ga0 + k0, la0);
        gl2lds16(ga1 + k0, la1);
        gl2lds16(gb0 + k0, lb0);
        gl2lds16(gb1 + k0, lb1);
        __syncthreads();

        s16x8 af[4], bfr[4];
        #pragma unroll
        for (int i = 0; i < 4; i++)
            af[i] = *(const s16x8*)(As + (wm * 64 + i * 16 + lm) * 32 + kq * 8);
        #pragma unroll
        for (int j = 0; j < 4; j++)
            bfr[j] = *(const s16x8*)(Bs + (wn * 64 + j * 16 + lm) * 32 + kq * 8);
        #pragma unroll
        for (int i = 0; i < 4; i++)
            #pragma unroll
            for (int j = 0; j < 4; j++)
                acc[i][j] = __builtin_amdgcn_mfma_f32_16x16x32_bf16(af[i], bfr[j], acc[i][j], 0, 0, 0);
        __syncthreads();
    }

    // epilogue: D row = kq*4 + r, col = lm (m89/m91-verified)
    #pragma unroll
    for (int j = 0; j < 4; j++) {
        int gcol = col0 + wn * 64 + j * 16 + lm;
        if (gcol >= N) continue;
        float bv = bias ? rd_adapt(bias, biasOff + gcol, isbf) : 0.0f;
        #pragma unroll
        for (int i = 0; i < 4; i++) {
            int grow0 = row0 + wm * 64 + i * 16 + kq * 4;
            #pragma unroll
            for (int r = 0; r < 4; r++) {
                float v = acc[i][j][r] * scale + bv;
                long long ci = (long long)(grow0 + r) * ldc + gcol;
                if (beta) v += (float)Cp[ci];
                if (Ep) v *= (float)Ep[ci];
                if (act) v = 0.5f * v * (1.0f + erff(v * 0.70710678118654752f));
                Cp[ci] = (bf16_t)v;
            }
        }
    }
}

// ---------------------------------------------------------------------------
// Adaptive tiled transpose with zero-padding beyond C columns.
// ---------------------------------------------------------------------------
__global__ __launch_bounds__(256)
void transpose_pad(const void* __restrict__ in, bf16_t* __restrict__ out,
                   int R, int C, int ldin, long long inOff,
                   long long sInB, long long sOutB, const int* __restrict__ flagp)
{
    __shared__ bf16_t t[32][33];
    int isbf = flagp ? *flagp : 1;
    int z = blockIdx.z;
    long long base = inOff + (long long)z * sInB;
    bf16_t* op = out + (long long)z * sOutB;
    int tx = threadIdx.x & 31, ty = threadIdx.x >> 5;
    int cb = blockIdx.x * 32, rb = blockIdx.y * 32;
    #pragma unroll
    for (int rr = ty; rr < 32; rr += 8) {
        int r = rb + rr, c = cb + tx;
        t[rr][tx] = (c < C) ? (bf16_t)rd_adapt(in, base + (long long)r * ldin + c, isbf)
                            : (bf16_t)0.0f;
    }
    __syncthreads();
    #pragma unroll
    for (int rr = ty; rr < 32; rr += 8) {
        int c = cb + rr;
        op[(long long)c * R + rb + tx] = t[tx][rr];
    }
}

// depthwise conv k=7, 'same' padding along S
__global__ __launch_bounds__(256)
void dconv_kernel(const bf16_t* __restrict__ ebuf, const void* __restrict__ dw,
                  bf16_t* __restrict__ out, const int* __restrict__ flagp)
{
    int isbf = *flagp;
    long long i = (long long)blockIdx.x * 256 + threadIdx.x;   // < B*S*H
    int c = (int)(i % HH);
    long long bs = i / HH;
    int s = (int)(bs % SS);
    float acc = 0.0f;
    #pragma unroll
    for (int k = 0; k < 7; k++) {
        int ss = s + k - 3;
        if (ss >= 0 && ss < SS)
            acc += (float)ebuf[(bs + (k - 3)) * HH + c] * rd_adapt(dw, c * 7 + k, isbf);
    }
    out[i] = (bf16_t)acc;
}

// ck softmax over k=7 per (b,s,h)
__global__ __launch_bounds__(256)
void ck_softmax(const bf16_t* __restrict__ ck, float* __restrict__ ckp)
{
    int i = blockIdx.x * 256 + threadIdx.x;   // < B*S*NH
    if (i >= BB * SS * NHH) return;
    int h = i % NHH;
    long long bs = i / NHH;
    const bf16_t* src = ck + bs * 64 + h * 7;
    float v[7], mx = -1e30f;
    #pragma unroll
    for (int k = 0; k < 7; k++) { v[k] = (float)src[k]; mx = fmaxf(mx, v[k]); }
    float sum = 0.0f;
    #pragma unroll
    for (int k = 0; k < 7; k++) { v[k] = expf(v[k] - mx); sum += v[k]; }
    float inv = 1.0f / sum;
    float* dst = ckp + bs * 56 + h * 7;
    #pragma unroll
    for (int k = 0; k < 7; k++) dst[k] = v[k] * inv;
}

// conv_out -> right half (cols 768..1535) of ctxcat [B*S,1536]
__global__ __launch_bounds__(256)
void conv_out_kernel(const bf16_t* __restrict__ co, const float* __restrict__ ckp,
                     bf16_t* __restrict__ ctxcat)
{
    long long i = (long long)blockIdx.x * 256 + threadIdx.x;   // < B*S*AH
    int hd = (int)(i % AHH);
    long long bs = i / AHH;
    int s = (int)(bs % SS);
    int h = hd / HDD;
    const float* w = ckp + bs * 56 + h * 7;
    float acc = 0.0f;
    #pragma unroll
    for (int k = 0; k < 7; k++) {
        int ss = s + k - 3;
        if (ss >= 0 && ss < SS)
            acc += (float)co[(bs + (k - 3)) * AHH + hd] * w[k];
    }
    ctxcat[bs * HH + AHH + hd] = (bf16_t)acc;
}

// row softmax, L=1024, in-place bf16, fp32 math
__global__ __launch_bounds__(256)
void softmax_rows(bf16_t* __restrict__ p)
{
    long long row = blockIdx.x;
    bf16_t* x = p + row * 1024;
    int tid = threadIdx.x;
    float v[4], mx = -1e30f;
    #pragma unroll
    for (int i = 0; i < 4; i++) { v[i] = (float)x[tid + i * 256]; mx = fmaxf(mx, v[i]); }
    __shared__ float sm[256];
    sm[tid] = mx; __syncthreads();
    for (int o = 128; o > 0; o >>= 1) { if (tid < o) sm[tid] = fmaxf(sm[tid], sm[tid + o]); __syncthreads(); }
    mx = sm[0]; __syncthreads();
    float sum = 0.0f;
    #pragma unroll
    for (int i = 0; i < 4; i++) { v[i] = expf(v[i] - mx); sum += v[i]; }
    sm[tid] = sum; __syncthreads();
    for (int o = 128; o > 0; o >>= 1) { if (tid < o) sm[tid] += sm[tid + o]; __syncthreads(); }
    float inv = 1.0f / sm[0];
    #pragma unroll
    for (int i = 0; i < 4; i++) x[tid + i * 256] = (bf16_t)(v[i] * inv);
}

// LayerNorm over 1536 of (y + res)
__global__ __launch_bounds__(256)
void ln_kernel(const bf16_t* __restrict__ y, const bf16_t* __restrict__ res,
               const void* __restrict__ g, const void* __restrict__ bta,
               bf16_t* __restrict__ outb, const int* __restrict__ flagp)
{
    int isbf = *flagp;
    long long row = blockIdx.x;
    const bf16_t* yp = y + row * HH;
    const bf16_t* rp = res + row * HH;
    int tid = threadIdx.x;
    float x[6], s = 0.0f, s2 = 0.0f;
    #pragma unroll
    for (int i = 0; i < 6; i++) {
        int c = tid + i * 256;
        float v = (float)yp[c] + (float)rp[c];
        x[i] = v; s += v; s2 += v * v;
    }
    __shared__ float sa[256], sb[256];
    sa[tid] = s; sb[tid] = s2; __syncthreads();
    for (int o = 128; o > 0; o >>= 1) {
        if (tid < o) { sa[tid] += sa[tid + o]; sb[tid] += sb[tid + o]; }
        __syncthreads();
    }
    float mean = sa[0] * (1.0f / HH);
    float var  = sb[0] * (1.0f / HH) - mean * mean;
    float inv  = rsqrtf(var + 1e-12f);
    #pragma unroll
    for (int i = 0; i < 6; i++) {
        int c = tid + i * 256;
        float v = (x[i] - mean) * inv * rd_adapt(g, c, isbf) + rd_adapt(bta, c, isbf);
        outb[row * HH + c] = (bf16_t)v;
    }
}

// pooled[b,c] = max_s lout[b,s,c]
__global__ __launch_bounds__(256)
void maxpool_kernel(const bf16_t* __restrict__ lo, float* __restrict__ pooled)
{
    int i = blockIdx.x * 256 + threadIdx.x;   // < B*H
    if (i >= BB * HH) return;
    int b = i / HH, c = i % HH;
    const bf16_t* p = lo + (long long)b * SS * HH + c;
    float m = -1e30f;
    for (int s = 0; s < SS; s++) m = fmaxf(m, (float)p[(long long)s * HH]);
    pooled[i] = m;
}

// logits[b] = pooled[b,:] . wd + bd
__global__ __launch_bounds__(256)
void decoder_kernel(const float* __restrict__ pooled, const void* __restrict__ wd,
                    const void* __restrict__ bd, void* __restrict__ out,
                    const int* __restrict__ flagp)
{
    int isbf = *flagp;
    int b = blockIdx.x;
    int tid = threadIdx.x;
    float s = 0.0f;
    #pragma unroll
    for (int i = 0; i < 6; i++) {
        int c = tid + i * 256;
        s += pooled[b * HH + c] * rd_adapt(wd, c, isbf);
    }
    __shared__ float sa[256];
    sa[tid] = s; __syncthreads();
    for (int o = 128; o > 0; o >>= 1) { if (tid < o) sa[tid] += sa[tid + o]; __syncthreads(); }
    if (tid == 0) {
        float r = sa[0] + rd_adapt(bd, 0, isbf);
        if (isbf) ((bf16_t*)out)[b] = (bf16_t)r;
        else      ((float*)out)[b]  = r;
    }
}

// ---------------------------------------------------------------------------
extern "C" void kernel_launch(void* const* d_in, const int* in_sizes, int n_in,
                              void* d_out, int out_size, void* d_ws, size_t ws_size,
                              hipStream_t stream)
{
    const void* embed = d_in[0];
    const void* wq  = d_in[1];  const void* bq  = d_in[2];
    const void* wk  = d_in[3];  const void* bk  = d_in[4];
    const void* wv  = d_in[5];  const void* bv  = d_in[6];
    const void* dw  = d_in[7];  const void* pw  = d_in[8];  const void* sep_b = d_in[9];
    const void* wck = d_in[10]; const void* bck = d_in[11];
    const void* wco = d_in[12]; const void* bco = d_in[13];
    const void* wso = d_in[14]; const void* bso = d_in[15];
    const void* ln1g = d_in[16]; const void* ln1b = d_in[17];
    const void* wi  = d_in[18]; const void* bi  = d_in[19];
    const void* wo  = d_in[20]; const void* bo  = d_in[21];
    const void* ln2g = d_in[22]; const void* ln2b = d_in[23];
    const void* wd  = d_in[24]; const void* bd  = d_in[25];
    (void)ws_size; (void)in_sizes; (void)n_in; (void)out_size;

    // ---- arena (~143.2 MB), identical layout to round 3 (known-good) ----
    char* ws = (char*)d_ws;
    char* X0 = ws;                          // 25.17 MB: qb,kbuf
    char* X1 = ws + 25165824;               // 37.75 MB: dconvb/sepb -> ckb/ckp -> scores -> ybuf -> interb -> lout
    char* X2 = ws + 62914560;               // 25.17 MB: vbuf + (cob -> vT)
    char* X4 = ws + 88080384;               // 25.17 MB: ctxcat -> attn
    char* X5 = ws + 113246208;              // 25.17 MB: ebuf -> y2
    char* XW = ws + 138412032;              //  4.72 MB: wT
    char* XP = ws + 143130624;              //  flag + pooled

    bf16_t* qb     = (bf16_t*)X0;                   // [8192,768]
    bf16_t* kbuf   = (bf16_t*)(X0 + 12582912);      // [8192,768]
    bf16_t* dconvb = (bf16_t*)X1;                   // [8192,1536]
    bf16_t* sepb   = (bf16_t*)(X1 + 25165824);      // [8192,768]
    bf16_t* ckb    = (bf16_t*)X1;                   // [8192,64]
    float*  ckp    = (float*) (X1 + 1310720);       // [8192,56] f32
    bf16_t* scores = (bf16_t*)X1;                   // [64,256,1024] (33.5 MB)
    bf16_t* ybuf   = (bf16_t*)X1;                   // [8192,1536]
    bf16_t* interb = (bf16_t*)X1;                   // [8192,1536] per FFN chunk
    bf16_t* lout   = (bf16_t*)X1;                   // [8192,1536]
    bf16_t* vbuf   = (bf16_t*)X2;                   // [8192,768]
    bf16_t* cob    = (bf16_t*)(X2 + 12582912);      // [8192,768]
    bf16_t* vT     = (bf16_t*)(X2 + 12582912);      // [8,768,1024]
    bf16_t* ctxcat = (bf16_t*)X4;                   // [8192,1536]
    bf16_t* attn   = (bf16_t*)X4;                   // [8192,1536]
    bf16_t* ebuf   = (bf16_t*)X5;                   // [8192,1536]
    bf16_t* y2     = (bf16_t*)X5;                   // [8192,1536]
    bf16_t* wT     = (bf16_t*)XW;
    int*    flag   = (int*)XP;
    float*  pooled = (float*)(XP + 256);            // [8,1536] f32

    dim3 blk(256);

    auto gemm = [&](const bf16_t* A, const bf16_t* Bt, bf16_t* C, const void* bias,
                    long long biasOff, const bf16_t* emul,
                    int M, int N, int Kd, int lda, int ldb, int ldc,
                    long long sAb, long long sAh, long long sBb, long long sBh,
                    long long sCb, long long sCh, int nb, int nh,
                    float scale, int act, int beta, int nlim) {
        dim3 g(M / 128, (N + 127) / 128, nb * nh);
        gemm_tile<<<g, blk, 0, stream>>>(A, Bt, C, bias, biasOff, emul, flag,
                                         M, N, Kd, lda, ldb, ldc,
                                         sAb, sAh, sBb, sBh, sCb, sCh, nh,
                                         scale, act, beta, nlim);
    };
    auto transpose = [&](const void* in, bf16_t* out, int R, int C, int Cpad, int ldin,
                         long long inOff, int batch, long long sInB, long long sOutB,
                         const int* fl) {
        dim3 g(Cpad / 32, R / 32, batch);
        transpose_pad<<<g, blk, 0, stream>>>(in, out, R, C, ldin, inOff, sInB, sOutB, fl);
    };

    // --- dtype probe + embed conversion ---
    detect_kernel<<<dim3(1), blk, 0, stream>>>(embed, flag);
    convert_embed<<<dim3(6144), blk, 0, stream>>>(embed, ebuf, flag);

    // --- projections ---
    transpose(wq, wT, 1536, 768, 768, 768, 0, 1, 0, 0, flag);
    gemm(ebuf, wT, qb,   bq, 0, nullptr, 8192, 768, 1536, HH, HH, AHH, 0,0,0,0,0,0, 1,1, 1.0f, 0, 0, 767);
    transpose(wk, wT, 1536, 768, 768, 768, 0, 1, 0, 0, flag);
    gemm(ebuf, wT, kbuf, bk, 0, nullptr, 8192, 768, 1536, HH, HH, AHH, 0,0,0,0,0,0, 1,1, 1.0f, 0, 0, 767);
    transpose(wv, wT, 1536, 768, 768, 768, 0, 1, 0, 0, flag);
    gemm(ebuf, wT, vbuf, bv, 0, nullptr, 8192, 768, 1536, HH, HH, AHH, 0,0,0,0,0,0, 1,1, 1.0f, 0, 0, 767);
    transpose(wco, wT, 1536, 768, 768, 768, 0, 1, 0, 0, flag);
    gemm(ebuf, wT, cob, bco, 0, nullptr, 8192, 768, 1536, HH, HH, AHH, 0,0,0,0,0,0, 1,1, 1.0f, 0, 0, 767);

    // --- separable conv: depthwise, then pointwise fused with *q ---
    dconv_kernel<<<dim3((BB * SS * HH) / 256), blk, 0, stream>>>(ebuf, dw, dconvb, flag);
    transpose(pw, wT, 1536, 768, 768, 768, 0, 1, 0, 0, flag);
    gemm(dconvb, wT, sepb, sep_b, 0, qb, 8192, 768, 1536, HH, HH, AHH, 0,0,0,0,0,0, 1,1, 1.0f, 0, 0, 767);

    // --- span conv kernels (wT padded to 128 rows, zero rows 56..127) ---
    transpose(wck, wT, 768, 56, 128, 56, 0, 1, 0, 0, flag);
    gemm(sepb, wT, ckb, bck, 0, nullptr, 8192, 56, 768, AHH, AHH, 64, 0,0,0,0,0,0, 1,1, 1.0f, 0, 0, 127);
    ck_softmax<<<dim3((BB * SS * NHH) / 256), blk, 0, stream>>>(ckb, ckp);
    conv_out_kernel<<<dim3((BB * SS * AHH) / 256), blk, 0, stream>>>(cob, ckp, ctxcat);

    // --- attention (4 q-chunks of 256 rows; scores = 33.5 MB in X1) ---
    transpose(vbuf, vT, 1024, 768, 768, 768, 0, 8, 1024ll * 768, 768ll * 1024, nullptr);
    const float ascale = 0.1020620726159658f;   // 1/sqrt(96)
    for (int ch = 0; ch < 4; ch++) {
        const bf16_t* qc = qb + (long long)ch * 256 * AHH;
        gemm(qc, kbuf, scores, nullptr, 0, nullptr, 256, 1024, 96,
             AHH, AHH, 1024,
             (long long)SS * AHH, 96,
             (long long)SS * AHH, 96,
             8ll * 256 * 1024, 256ll * 1024,
             BB, NHH, ascale, 0, 0, 1023);
        softmax_rows<<<dim3(64 * 256), blk, 0, stream>>>(scores);
        // PV: N=96 < 128 tile; B-row staging clamped to 95, cols 96..127 discarded
        gemm(scores, vT, ctxcat + (long long)ch * 256 * HH, nullptr, 0, nullptr,
             256, 96, 1024,
             1024, 1024, HH,
             8ll * 256 * 1024, 256ll * 1024,
             768ll * 1024, 96ll * 1024,
             (long long)SS * HH, 96,
             BB, NHH, 1.0f, 0, 0, 95);
    }

    // --- self output + LN1 ---
    transpose(wso, wT, 1536, 1536, 1536, 1536, 0, 1, 0, 0, flag);
    gemm(ctxcat, wT, ybuf, bso, 0, nullptr, 8192, 1536, 1536, HH, HH, HH, 0,0,0,0,0,0, 1,1, 1.0f, 0, 0, 1535);
    ln_kernel<<<dim3(8192), blk, 0, stream>>>(ybuf, ebuf, ln1g, ln1b, attn, flag);

    // --- FFN in 2 chunks of IM=1536 + LN2 ---
    for (int c = 0; c < 2; c++) {
        transpose(wi, wT, 1536, 1536, 1536, 3072, (long long)c * 1536, 1, 0, 0, flag);
        gemm(attn, wT, interb, bi, (long long)c * 1536, nullptr,
             8192, 1536, 1536, HH, 1536, 1536, 0,0,0,0,0,0, 1,1, 1.0f, 1, 0, 1535);
        transpose(wo, wT, 1536, 1536, 1536, 1536, (long long)c * 1536 * 1536, 1, 0, 0, flag);
        gemm(interb, wT, y2, (c == 0 ? bo : nullptr), 0, nullptr,
             8192, 1536, 1536, 1536, 1536, HH, 0,0,0,0,0,0, 1,1, 1.0f, 0, (c == 0 ? 0 : 1), 1535);
    }
    ln_kernel<<<dim3(8192), blk, 0, stream>>>(y2, attn, ln2g, ln2b, lout, flag);

    // --- pool + decode ---
    maxpool_kernel<<<dim3((BB * HH + 255) / 256), blk, 0, stream>>>(lout, pooled);
    decoder_kernel<<<dim3(BB), blk, 0, stream>>>(pooled, wd, bd, d_out, flag);
}

// Round 5
// 1090.308 us; speedup vs baseline: 2.4423x; 1.3156x over previous
//
#include <hip/hip_runtime.h>

// ---------------------------------------------------------------------------
// ConvBERT layer forward, bf16 compute / fp32 accumulate.
// B=8 S=1024 H=1536 NH=8 HD=96 AH=768 K=7 IM=3072
// Round 5: fused flash attention (online softmax, LDS P-transpose round trip)
//          + two-phase maxpool (was 162us latency-bound).
// ---------------------------------------------------------------------------

typedef __bf16 bf16_t;
typedef short s16x8 __attribute__((ext_vector_type(8)));   // 8 bf16 in 4 VGPRs
typedef float f32x4 __attribute__((ext_vector_type(4)));

#define BB  8
#define SS  1024
#define HH  1536
#define NHH 8
#define HDD 96
#define AHH 768
#define IMM 3072

__device__ __forceinline__ float rd_adapt(const void* p, long long i, int isbf) {
    return isbf ? (float)((const bf16_t*)p)[i] : ((const float*)p)[i];
}

// async global->LDS, 16B per lane; lds base must be wave-uniform
__device__ __forceinline__ void gl2lds16(const bf16_t* g, bf16_t* l) {
    __builtin_amdgcn_global_load_lds(
        (__attribute__((address_space(1))) const void*)g,
        (__attribute__((address_space(3))) void*)l, 16, 0, 0);
}

// ---------------------------------------------------------------------------
// dtype probe: bf16 vs fp32 inputs. flag=1 -> bf16.
// ---------------------------------------------------------------------------
__global__ __launch_bounds__(256)
void detect_kernel(const void* __restrict__ embed, int* __restrict__ flag)
{
    __shared__ int cnt[256];
    int t = threadIdx.x;
    float x = (float)((const bf16_t*)embed)[t];
    float a = fabsf(x);
    cnt[t] = (a > 1e-3f && a < 50.0f) ? 1 : 0;
    __syncthreads();
    for (int o = 128; o > 0; o >>= 1) { if (t < o) cnt[t] += cnt[t + o]; __syncthreads(); }
    if (t == 0) *flag = (cnt[0] >= 205) ? 1 : 0;
}

__global__ __launch_bounds__(256)
void convert_embed(const void* __restrict__ in, bf16_t* __restrict__ out,
                   const int* __restrict__ flagp)
{
    int isbf = *flagp;
    long long i0 = ((long long)blockIdx.x * 256 + threadIdx.x) * 8;
    if (isbf) {
        *(s16x8*)(out + i0) = *(const s16x8*)((const bf16_t*)in + i0);
    } else {
        const float* f = (const float*)in;
        #pragma unroll
        for (int j = 0; j < 8; j++) out[i0 + j] = (bf16_t)f[i0 + j];
    }
}

// ---------------------------------------------------------------------------
// LDS-staged batched GEMM (m97 structure): 128x128 tile, BK=32, 4 waves.
// ---------------------------------------------------------------------------
__global__ __launch_bounds__(256)
void gemm_tile(const bf16_t* __restrict__ A, const bf16_t* __restrict__ Bt,
               bf16_t* __restrict__ C, const void* __restrict__ bias, long long biasOff,
               const bf16_t* __restrict__ emul, const int* __restrict__ flagp,
               int M, int N, int Kd, int lda, int ldb, int ldc,
               long long sAb, long long sAh, long long sBb, long long sBh,
               long long sCb, long long sCh, int nh, float scale, int act, int beta,
               int nlim)
{
    __shared__ bf16_t As[128 * 32];
    __shared__ bf16_t Bs[128 * 32];

    int isbf = flagp ? *flagp : 1;
    int z  = blockIdx.z;
    int zb = z / nh, zh = z - zb * nh;
    const bf16_t* Ap = A  + zb * sAb + zh * sAh;
    const bf16_t* Bp = Bt + zb * sBb + zh * sBh;
    bf16_t*       Cp = C  + zb * sCb + zh * sCh;
    const bf16_t* Ep = emul ? (emul + zb * sCb + zh * sCh) : (const bf16_t*)nullptr;

    int tid  = threadIdx.x;
    int wave = tid >> 6, lane = tid & 63;
    int wm = wave >> 1, wn = wave & 1;
    int row0 = blockIdx.x * 128;
    int col0 = blockIdx.y * 128;
    int lm = lane & 15;
    int kq = lane >> 4;

    int sr = tid >> 2;
    int sc = (tid & 3) * 8;
    const bf16_t* ga0 = Ap + (long long)(row0 + sr) * lda + sc;
    const bf16_t* ga1 = Ap + (long long)(row0 + 64 + sr) * lda + sc;
    int br0 = min(col0 + sr, nlim);
    int br1 = min(col0 + 64 + sr, nlim);
    const bf16_t* gb0 = Bp + (long long)br0 * ldb + sc;
    const bf16_t* gb1 = Bp + (long long)br1 * ldb + sc;
    bf16_t* la0 = As + wave * 512;
    bf16_t* la1 = As + 2048 + wave * 512;
    bf16_t* lb0 = Bs + wave * 512;
    bf16_t* lb1 = Bs + 2048 + wave * 512;

    f32x4 acc[4][4] = {};

    for (int k0 = 0; k0 < Kd; k0 += 32) {
        gl2lds16(ga0 + k0, la0);
        gl2lds16(ga1 + k0, la1);
        gl2lds16(gb0 + k0, lb0);
        gl2lds16(gb1 + k0, lb1);
        __syncthreads();

        s16x8 af[4], bfr[4];
        #pragma unroll
        for (int i = 0; i < 4; i++)
            af[i] = *(const s16x8*)(As + (wm * 64 + i * 16 + lm) * 32 + kq * 8);
        #pragma unroll
        for (int j = 0; j < 4; j++)
            bfr[j] = *(const s16x8*)(Bs + (wn * 64 + j * 16 + lm) * 32 + kq * 8);
        #pragma unroll
        for (int i = 0; i < 4; i++)
            #pragma unroll
            for (int j = 0; j < 4; j++)
                acc[i][j] = __builtin_amdgcn_mfma_f32_16x16x32_bf16(af[i], bfr[j], acc[i][j], 0, 0, 0);
        __syncthreads();
    }

    #pragma unroll
    for (int j = 0; j < 4; j++) {
        int gcol = col0 + wn * 64 + j * 16 + lm;
        if (gcol >= N) continue;
        float bv = bias ? rd_adapt(bias, biasOff + gcol, isbf) : 0.0f;
        #pragma unroll
        for (int i = 0; i < 4; i++) {
            int grow0 = row0 + wm * 64 + i * 16 + kq * 4;
            #pragma unroll
            for (int r = 0; r < 4; r++) {
                float v = acc[i][j][r] * scale + bv;
                long long ci = (long long)(grow0 + r) * ldc + gcol;
                if (beta) v += (float)Cp[ci];
                if (Ep) v *= (float)Ep[ci];
                if (act) v = 0.5f * v * (1.0f + erff(v * 0.70710678118654752f));
                Cp[ci] = (bf16_t)v;
            }
        }
    }
}

// ---------------------------------------------------------------------------
// Fused flash attention. grid = (8 q-tiles of 128, 64 bh), block = 256.
// Per wave: 32 q-rows. Online softmax; P C-layout -> A-layout via padded LDS.
// Q,K from row-major [S,768] (+h*96); V^T from vT [8][768][1024].
// Output -> ctxcat left half (col offset h*96).
// ---------------------------------------------------------------------------
__global__ __launch_bounds__(256, 2)
void flash_attn(const bf16_t* __restrict__ qb, const bf16_t* __restrict__ kbuf,
                const bf16_t* __restrict__ vT, bf16_t* __restrict__ ctxcat)
{
    const float ascale = 0.1020620726159658f;   // 1/sqrt(96)
    __shared__ bf16_t Pl[4 * 32 * 136];         // per-wave P[32][136] (pad 8)

    int bh = blockIdx.y;
    int b = bh >> 3, h = bh & 7;
    const bf16_t* Qp = qb   + (long long)b * SS * AHH + h * HDD;
    const bf16_t* Kp = kbuf + (long long)b * SS * AHH + h * HDD;
    const bf16_t* Vt = vT   + (long long)b * AHH * SS + (long long)h * HDD * SS;
    bf16_t*       Op = ctxcat + (long long)b * SS * HH + h * HDD;

    int tid = threadIdx.x, wave = tid >> 6, lane = tid & 63;
    int lm = lane & 15, kq = lane >> 4;
    int q0 = blockIdx.x * 128 + wave * 32;
    bf16_t* Pw = Pl + wave * 32 * 136;

    // Q fragments: 2 m-tiles x 3 k-frags, resident
    s16x8 aq[2][3];
    #pragma unroll
    for (int i = 0; i < 2; i++)
        #pragma unroll
        for (int kf = 0; kf < 3; kf++)
            aq[i][kf] = *(const s16x8*)(Qp + (long long)(q0 + i * 16 + lm) * AHH + kf * 32 + kq * 8);

    f32x4 Oacc[2][6] = {};
    float mrow[2][4], lrow[2][4];
    #pragma unroll
    for (int i = 0; i < 2; i++)
        #pragma unroll
        for (int r = 0; r < 4; r++) { mrow[i][r] = -1e30f; lrow[i][r] = 0.0f; }

    for (int kt = 0; kt < 8; kt++) {
        // ---- S = Q K^T (raw) ----
        f32x4 S[2][8] = {};
        #pragma unroll
        for (int j = 0; j < 8; j++) {
            s16x8 bk[3];
            #pragma unroll
            for (int kf = 0; kf < 3; kf++)
                bk[kf] = *(const s16x8*)(Kp + (long long)(kt * 128 + j * 16 + lm) * AHH + kf * 32 + kq * 8);
            #pragma unroll
            for (int i = 0; i < 2; i++)
                #pragma unroll
                for (int kf = 0; kf < 3; kf++)
                    S[i][j] = __builtin_amdgcn_mfma_f32_16x16x32_bf16(aq[i][kf], bk[kf], S[i][j], 0, 0, 0);
        }

        // ---- online softmax: row max across 128 cols ----
        float mnew[2][4];
        #pragma unroll
        for (int i = 0; i < 2; i++) {
            #pragma unroll
            for (int r = 0; r < 4; r++) {
                float mx = -1e30f;
                #pragma unroll
                for (int j = 0; j < 8; j++) mx = fmaxf(mx, S[i][j][r]);
                #pragma unroll
                for (int msk = 1; msk <= 8; msk <<= 1) mx = fmaxf(mx, __shfl_xor(mx, msk));
                mnew[i][r] = fmaxf(mrow[i][r], mx * ascale);
            }
        }
        // rescale running state
        #pragma unroll
        for (int i = 0; i < 2; i++) {
            #pragma unroll
            for (int r = 0; r < 4; r++) {
                float al = __expf(mrow[i][r] - mnew[i][r]);
                lrow[i][r] *= al;
                #pragma unroll
                for (int n = 0; n < 6; n++) Oacc[i][n][r] *= al;
                mrow[i][r] = mnew[i][r];
            }
        }
        // P = exp(S*ascale - m), accumulate row sums, store to LDS
        float psum[2][4] = {};
        __syncthreads();   // protect LDS WAR from previous iteration's reads
        #pragma unroll
        for (int i = 0; i < 2; i++) {
            #pragma unroll
            for (int j = 0; j < 8; j++) {
                #pragma unroll
                for (int r = 0; r < 4; r++) {
                    float p = __expf(S[i][j][r] * ascale - mnew[i][r]);
                    psum[i][r] += p;
                    Pw[(i * 16 + kq * 4 + r) * 136 + j * 16 + lm] = (bf16_t)p;
                }
            }
        }
        #pragma unroll
        for (int i = 0; i < 2; i++) {
            #pragma unroll
            for (int r = 0; r < 4; r++) {
                float t = psum[i][r];
                #pragma unroll
                for (int msk = 1; msk <= 8; msk <<= 1) t += __shfl_xor(t, msk);
                lrow[i][r] += t;
            }
        }
        __syncthreads();   // P visible (also cross-wave safety)

        // ---- O += P V : A-frags from LDS, B-frags from vT global ----
        s16x8 ap[2][4];
        #pragma unroll
        for (int i = 0; i < 2; i++)
            #pragma unroll
            for (int kf = 0; kf < 4; kf++)
                ap[i][kf] = *(const s16x8*)(Pw + (i * 16 + lm) * 136 + kf * 32 + kq * 8);
        #pragma unroll
        for (int n = 0; n < 6; n++) {
            s16x8 bv[4];
            #pragma unroll
            for (int kf = 0; kf < 4; kf++)
                bv[kf] = *(const s16x8*)(Vt + (long long)(n * 16 + lm) * SS + kt * 128 + kf * 32 + kq * 8);
            #pragma unroll
            for (int i = 0; i < 2; i++)
                #pragma unroll
                for (int kf = 0; kf < 4; kf++)
                    Oacc[i][n] = __builtin_amdgcn_mfma_f32_16x16x32_bf16(ap[i][kf], bv[kf], Oacc[i][n], 0, 0, 0);
        }
    }

    // epilogue: O /= l, C-layout write
    #pragma unroll
    for (int i = 0; i < 2; i++) {
        #pragma unroll
        for (int n = 0; n < 6; n++) {
            #pragma unroll
            for (int r = 0; r < 4; r++) {
                int row = q0 + i * 16 + kq * 4 + r;
                int col = n * 16 + lm;
                Op[(long long)row * HH + col] = (bf16_t)(Oacc[i][n][r] / lrow[i][r]);
            }
        }
    }
}

// ---------------------------------------------------------------------------
// Adaptive tiled transpose with zero-padding beyond C columns.
// ---------------------------------------------------------------------------
__global__ __launch_bounds__(256)
void transpose_pad(const void* __restrict__ in, bf16_t* __restrict__ out,
                   int R, int C, int ldin, long long inOff,
                   long long sInB, long long sOutB, const int* __restrict__ flagp)
{
    __shared__ bf16_t t[32][33];
    int isbf = flagp ? *flagp : 1;
    int z = blockIdx.z;
    long long base = inOff + (long long)z * sInB;
    bf16_t* op = out + (long long)z * sOutB;
    int tx = threadIdx.x & 31, ty = threadIdx.x >> 5;
    int cb = blockIdx.x * 32, rb = blockIdx.y * 32;
    #pragma unroll
    for (int rr = ty; rr < 32; rr += 8) {
        int r = rb + rr, c = cb + tx;
        t[rr][tx] = (c < C) ? (bf16_t)rd_adapt(in, base + (long long)r * ldin + c, isbf)
                            : (bf16_t)0.0f;
    }
    __syncthreads();
    #pragma unroll
    for (int rr = ty; rr < 32; rr += 8) {
        int c = cb + rr;
        op[(long long)c * R + rb + tx] = t[tx][rr];
    }
}

// depthwise conv k=7, 'same' padding along S
__global__ __launch_bounds__(256)
void dconv_kernel(const bf16_t* __restrict__ ebuf, const void* __restrict__ dw,
                  bf16_t* __restrict__ out, const int* __restrict__ flagp)
{
    int isbf = *flagp;
    long long i = (long long)blockIdx.x * 256 + threadIdx.x;   // < B*S*H
    int c = (int)(i % HH);
    long long bs = i / HH;
    int s = (int)(bs % SS);
    float acc = 0.0f;
    #pragma unroll
    for (int k = 0; k < 7; k++) {
        int ss = s + k - 3;
        if (ss >= 0 && ss < SS)
            acc += (float)ebuf[(bs + (k - 3)) * HH + c] * rd_adapt(dw, c * 7 + k, isbf);
    }
    out[i] = (bf16_t)acc;
}

// ck softmax over k=7 per (b,s,h)
__global__ __launch_bounds__(256)
void ck_softmax(const bf16_t* __restrict__ ck, float* __restrict__ ckp)
{
    int i = blockIdx.x * 256 + threadIdx.x;   // < B*S*NH
    if (i >= BB * SS * NHH) return;
    int h = i % NHH;
    long long bs = i / NHH;
    const bf16_t* src = ck + bs * 64 + h * 7;
    float v[7], mx = -1e30f;
    #pragma unroll
    for (int k = 0; k < 7; k++) { v[k] = (float)src[k]; mx = fmaxf(mx, v[k]); }
    float sum = 0.0f;
    #pragma unroll
    for (int k = 0; k < 7; k++) { v[k] = expf(v[k] - mx); sum += v[k]; }
    float inv = 1.0f / sum;
    float* dst = ckp + bs * 56 + h * 7;
    #pragma unroll
    for (int k = 0; k < 7; k++) dst[k] = v[k] * inv;
}

// conv_out -> right half (cols 768..1535) of ctxcat [B*S,1536]
__global__ __launch_bounds__(256)
void conv_out_kernel(const bf16_t* __restrict__ co, const float* __restrict__ ckp,
                     bf16_t* __restrict__ ctxcat)
{
    long long i = (long long)blockIdx.x * 256 + threadIdx.x;   // < B*S*AH
    int hd = (int)(i % AHH);
    long long bs = i / AHH;
    int s = (int)(bs % SS);
    int h = hd / HDD;
    const float* w = ckp + bs * 56 + h * 7;
    float acc = 0.0f;
    #pragma unroll
    for (int k = 0; k < 7; k++) {
        int ss = s + k - 3;
        if (ss >= 0 && ss < SS)
            acc += (float)co[(bs + (k - 3)) * AHH + hd] * w[k];
    }
    ctxcat[bs * HH + AHH + hd] = (bf16_t)acc;
}

// LayerNorm over 1536 of (y + res)
__global__ __launch_bounds__(256)
void ln_kernel(const bf16_t* __restrict__ y, const bf16_t* __restrict__ res,
               const void* __restrict__ g, const void* __restrict__ bta,
               bf16_t* __restrict__ outb, const int* __restrict__ flagp)
{
    int isbf = *flagp;
    long long row = blockIdx.x;
    const bf16_t* yp = y + row * HH;
    const bf16_t* rp = res + row * HH;
    int tid = threadIdx.x;
    float x[6], s = 0.0f, s2 = 0.0f;
    #pragma unroll
    for (int i = 0; i < 6; i++) {
        int c = tid + i * 256;
        float v = (float)yp[c] + (float)rp[c];
        x[i] = v; s += v; s2 += v * v;
    }
    __shared__ float sa[256], sb[256];
    sa[tid] = s; sb[tid] = s2; __syncthreads();
    for (int o = 128; o > 0; o >>= 1) {
        if (tid < o) { sa[tid] += sa[tid + o]; sb[tid] += sb[tid + o]; }
        __syncthreads();
    }
    float mean = sa[0] * (1.0f / HH);
    float var  = sb[0] * (1.0f / HH) - mean * mean;
    float inv  = rsqrtf(var + 1e-12f);
    #pragma unroll
    for (int i = 0; i < 6; i++) {
        int c = tid + i * 256;
        float v = (x[i] - mean) * inv * rd_adapt(g, c, isbf) + rd_adapt(bta, c, isbf);
        outb[row * HH + c] = (bf16_t)v;
    }
}

// two-phase maxpool: phase 1 = 32-row chunks, coalesced
__global__ __launch_bounds__(256)
void maxpool_p1(const bf16_t* __restrict__ lo, float* __restrict__ part)
{
    int sc = blockIdx.x, b = blockIdx.y;       // 32 chunks x 8 batches
    int tid = threadIdx.x;
    const bf16_t* p = lo + ((long long)b * SS + sc * 32) * HH;
    float m[6];
    #pragma unroll
    for (int k = 0; k < 6; k++) m[k] = -1e30f;
    for (int r = 0; r < 32; r++)
        #pragma unroll
        for (int k = 0; k < 6; k++)
            m[k] = fmaxf(m[k], (float)p[(long long)r * HH + k * 256 + tid]);
    #pragma unroll
    for (int k = 0; k < 6; k++)
        part[((long long)b * 32 + sc) * HH + k * 256 + tid] = m[k];
}

__global__ __launch_bounds__(256)
void maxpool_p2(const float* __restrict__ part, float* __restrict__ pooled)
{
    int i = blockIdx.x * 256 + threadIdx.x;    // < B*H
    if (i >= BB * HH) return;
    int b = i / HH, c = i % HH;
    float m = -1e30f;
    for (int ch = 0; ch < 32; ch++) m = fmaxf(m, part[((long long)b * 32 + ch) * HH + c]);
    pooled[i] = m;
}

// logits[b] = pooled[b,:] . wd + bd
__global__ __launch_bounds__(256)
void decoder_kernel(const float* __restrict__ pooled, const void* __restrict__ wd,
                    const void* __restrict__ bd, void* __restrict__ out,
                    const int* __restrict__ flagp)
{
    int isbf = *flagp;
    int b = blockIdx.x;
    int tid = threadIdx.x;
    float s = 0.0f;
    #pragma unroll
    for (int i = 0; i < 6; i++) {
        int c = tid + i * 256;
        s += pooled[b * HH + c] * rd_adapt(wd, c, isbf);
    }
    __shared__ float sa[256];
    sa[tid] = s; __syncthreads();
    for (int o = 128; o > 0; o >>= 1) { if (tid < o) sa[tid] += sa[tid + o]; __syncthreads(); }
    if (tid == 0) {
        float r = sa[0] + rd_adapt(bd, 0, isbf);
        if (isbf) ((bf16_t*)out)[b] = (bf16_t)r;
        else      ((float*)out)[b]  = r;
    }
}

// ---------------------------------------------------------------------------
extern "C" void kernel_launch(void* const* d_in, const int* in_sizes, int n_in,
                              void* d_out, int out_size, void* d_ws, size_t ws_size,
                              hipStream_t stream)
{
    const void* embed = d_in[0];
    const void* wq  = d_in[1];  const void* bq  = d_in[2];
    const void* wk  = d_in[3];  const void* bk  = d_in[4];
    const void* wv  = d_in[5];  const void* bv  = d_in[6];
    const void* dw  = d_in[7];  const void* pw  = d_in[8];  const void* sep_b = d_in[9];
    const void* wck = d_in[10]; const void* bck = d_in[11];
    const void* wco = d_in[12]; const void* bco = d_in[13];
    const void* wso = d_in[14]; const void* bso = d_in[15];
    const void* ln1g = d_in[16]; const void* ln1b = d_in[17];
    const void* wi  = d_in[18]; const void* bi  = d_in[19];
    const void* wo  = d_in[20]; const void* bo  = d_in[21];
    const void* ln2g = d_in[22]; const void* ln2b = d_in[23];
    const void* wd  = d_in[24]; const void* bd  = d_in[25];
    (void)ws_size; (void)in_sizes; (void)n_in; (void)out_size;

    // ---- arena (~143.2 MB), identical layout to round 4 (known-good) ----
    char* ws = (char*)d_ws;
    char* X0 = ws;                          // 25.17 MB: qb,kbuf -> maxpool partials
    char* X1 = ws + 25165824;               // 37.75 MB: dconvb/sepb -> ckb/ckp -> ybuf -> interb -> lout
    char* X2 = ws + 62914560;               // 25.17 MB: vbuf + (cob -> vT)
    char* X4 = ws + 88080384;               // 25.17 MB: ctxcat -> attn
    char* X5 = ws + 113246208;              // 25.17 MB: ebuf -> y2
    char* XW = ws + 138412032;              //  4.72 MB: wT
    char* XP = ws + 143130624;              //  flag + pooled

    bf16_t* qb     = (bf16_t*)X0;                   // [8192,768]
    bf16_t* kbuf   = (bf16_t*)(X0 + 12582912);      // [8192,768]
    float*  mpart  = (float*)X0;                    // [8,32,1536] f32 (after attn)
    bf16_t* dconvb = (bf16_t*)X1;                   // [8192,1536]
    bf16_t* sepb   = (bf16_t*)(X1 + 25165824);      // [8192,768]
    bf16_t* ckb    = (bf16_t*)X1;                   // [8192,64]
    float*  ckp    = (float*) (X1 + 1310720);       // [8192,56] f32
    bf16_t* ybuf   = (bf16_t*)X1;                   // [8192,1536]
    bf16_t* interb = (bf16_t*)X1;                   // [8192,1536] per FFN chunk
    bf16_t* lout   = (bf16_t*)X1;                   // [8192,1536]
    bf16_t* vbuf   = (bf16_t*)X2;                   // [8192,768]
    bf16_t* cob    = (bf16_t*)(X2 + 12582912);      // [8192,768]
    bf16_t* vT     = (bf16_t*)(X2 + 12582912);      // [8,768,1024]
    bf16_t* ctxcat = (bf16_t*)X4;                   // [8192,1536]
    bf16_t* attn   = (bf16_t*)X4;                   // [8192,1536]
    bf16_t* ebuf   = (bf16_t*)X5;                   // [8192,1536]
    bf16_t* y2     = (bf16_t*)X5;                   // [8192,1536]
    bf16_t* wT     = (bf16_t*)XW;
    int*    flag   = (int*)XP;
    float*  pooled = (float*)(XP + 256);            // [8,1536] f32

    dim3 blk(256);

    auto gemm = [&](const bf16_t* A, const bf16_t* Bt, bf16_t* C, const void* bias,
                    long long biasOff, const bf16_t* emul,
                    int M, int N, int Kd, int lda, int ldb, int ldc,
                    long long sAb, long long sAh, long long sBb, long long sBh,
                    long long sCb, long long sCh, int nb, int nh,
                    float scale, int act, int beta, int nlim) {
        dim3 g(M / 128, (N + 127) / 128, nb * nh);
        gemm_tile<<<g, blk, 0, stream>>>(A, Bt, C, bias, biasOff, emul, flag,
                                         M, N, Kd, lda, ldb, ldc,
                                         sAb, sAh, sBb, sBh, sCb, sCh, nh,
                                         scale, act, beta, nlim);
    };
    auto transpose = [&](const void* in, bf16_t* out, int R, int C, int Cpad, int ldin,
                         long long inOff, int batch, long long sInB, long long sOutB,
                         const int* fl) {
        dim3 g(Cpad / 32, R / 32, batch);
        transpose_pad<<<g, blk, 0, stream>>>(in, out, R, C, ldin, inOff, sInB, sOutB, fl);
    };

    // --- dtype probe + embed conversion ---
    detect_kernel<<<dim3(1), blk, 0, stream>>>(embed, flag);
    convert_embed<<<dim3(6144), blk, 0, stream>>>(embed, ebuf, flag);

    // --- projections ---
    transpose(wq, wT, 1536, 768, 768, 768, 0, 1, 0, 0, flag);
    gemm(ebuf, wT, qb,   bq, 0, nullptr, 8192, 768, 1536, HH, HH, AHH, 0,0,0,0,0,0, 1,1, 1.0f, 0, 0, 767);
    transpose(wk, wT, 1536, 768, 768, 768, 0, 1, 0, 0, flag);
    gemm(ebuf, wT, kbuf, bk, 0, nullptr, 8192, 768, 1536, HH, HH, AHH, 0,0,0,0,0,0, 1,1, 1.0f, 0, 0, 767);
    transpose(wv, wT, 1536, 768, 768, 768, 0, 1, 0, 0, flag);
    gemm(ebuf, wT, vbuf, bv, 0, nullptr, 8192, 768, 1536, HH, HH, AHH, 0,0,0,0,0,0, 1,1, 1.0f, 0, 0, 767);
    transpose(wco, wT, 1536, 768, 768, 768, 0, 1, 0, 0, flag);
    gemm(ebuf, wT, cob, bco, 0, nullptr, 8192, 768, 1536, HH, HH, AHH, 0,0,0,0,0,0, 1,1, 1.0f, 0, 0, 767);

    // --- separable conv: depthwise, then pointwise fused with *q ---
    dconv_kernel<<<dim3((BB * SS * HH) / 256), blk, 0, stream>>>(ebuf, dw, dconvb, flag);
    transpose(pw, wT, 1536, 768, 768, 768, 0, 1, 0, 0, flag);
    gemm(dconvb, wT, sepb, sep_b, 0, qb, 8192, 768, 1536, HH, HH, AHH, 0,0,0,0,0,0, 1,1, 1.0f, 0, 0, 767);

    // --- span conv kernels (wT padded to 128 rows, zero rows 56..127) ---
    transpose(wck, wT, 768, 56, 128, 56, 0, 1, 0, 0, flag);
    gemm(sepb, wT, ckb, bck, 0, nullptr, 8192, 56, 768, AHH, AHH, 64, 0,0,0,0,0,0, 1,1, 1.0f, 0, 0, 127);
    ck_softmax<<<dim3((BB * SS * NHH) / 256), blk, 0, stream>>>(ckb, ckp);
    conv_out_kernel<<<dim3((BB * SS * AHH) / 256), blk, 0, stream>>>(cob, ckp, ctxcat);

    // --- fused flash attention (writes ctxcat cols 0..767) ---
    transpose(vbuf, vT, 1024, 768, 768, 768, 0, 8, 1024ll * 768, 768ll * 1024, nullptr);
    flash_attn<<<dim3(8, 64), blk, 0, stream>>>(qb, kbuf, vT, ctxcat);

    // --- self output + LN1 ---
    transpose(wso, wT, 1536, 1536, 1536, 1536, 0, 1, 0, 0, flag);
    gemm(ctxcat, wT, ybuf, bso, 0, nullptr, 8192, 1536, 1536, HH, HH, HH, 0,0,0,0,0,0, 1,1, 1.0f, 0, 0, 1535);
    ln_kernel<<<dim3(8192), blk, 0, stream>>>(ybuf, ebuf, ln1g, ln1b, attn, flag);

    // --- FFN in 2 chunks of IM=1536 + LN2 ---
    for (int c = 0; c < 2; c++) {
        transpose(wi, wT, 1536, 1536, 1536, 3072, (long long)c * 1536, 1, 0, 0, flag);
        gemm(attn, wT, interb, bi, (long long)c * 1536, nullptr,
             8192, 1536, 1536, HH, 1536, 1536, 0,0,0,0,0,0, 1,1, 1.0f, 1, 0, 1535);
        transpose(wo, wT, 1536, 1536, 1536, 1536, (long long)c * 1536 * 1536, 1, 0, 0, flag);
        gemm(interb, wT, y2, (c == 0 ? bo : nullptr), 0, nullptr,
             8192, 1536, 1536, 1536, 1536, HH, 0,0,0,0,0,0, 1,1, 1.0f, 0, (c == 0 ? 0 : 1), 1535);
    }
    ln_kernel<<<dim3(8192), blk, 0, stream>>>(y2, attn, ln2g, ln2b, lout, flag);

    // --- pool + decode (two-phase; partials in dead X0) ---
    maxpool_p1<<<dim3(32, 8), blk, 0, stream>>>(lout, mpart);
    maxpool_p2<<<dim3(48), blk, 0, stream>>>(mpart, pooled);
    decoder_kernel<<<dim3(BB), blk, 0, stream>>>(pooled, wd, bd, d_out, flag);
}

// Round 6
// 972.149 us; speedup vs baseline: 2.7391x; 1.1215x over previous
//
#include <hip/hip_runtime.h>

// ---------------------------------------------------------------------------
// ConvBERT layer forward, bf16 compute / fp32 accumulate.
// B=8 S=1024 H=1536 NH=8 HD=96 AH=768 K=7 IM=3072
// Round 6: flash-attn XCD-locality grid swizzle (bh fastest -> same-XCD L2
//          K/V reuse), merged Q/K/V/co projection GEMM (N=3072, 6 blk/CU),
//          full-width FFN GEMMs. Arena re-aliased, still 143.2 MB.
// ---------------------------------------------------------------------------

typedef __bf16 bf16_t;
typedef short s16x8 __attribute__((ext_vector_type(8)));   // 8 bf16 in 4 VGPRs
typedef float f32x4 __attribute__((ext_vector_type(4)));

#define BB  8
#define SS  1024
#define HH  1536
#define NHH 8
#define HDD 96
#define AHH 768
#define IMM 3072

__device__ __forceinline__ float rd_adapt(const void* p, long long i, int isbf) {
    return isbf ? (float)((const bf16_t*)p)[i] : ((const float*)p)[i];
}

// async global->LDS, 16B per lane; lds base must be wave-uniform
__device__ __forceinline__ void gl2lds16(const bf16_t* g, bf16_t* l) {
    __builtin_amdgcn_global_load_lds(
        (__attribute__((address_space(1))) const void*)g,
        (__attribute__((address_space(3))) void*)l, 16, 0, 0);
}

// ---------------------------------------------------------------------------
// dtype probe: bf16 vs fp32 inputs. flag=1 -> bf16.
// ---------------------------------------------------------------------------
__global__ __launch_bounds__(256)
void detect_kernel(const void* __restrict__ embed, int* __restrict__ flag)
{
    __shared__ int cnt[256];
    int t = threadIdx.x;
    float x = (float)((const bf16_t*)embed)[t];
    float a = fabsf(x);
    cnt[t] = (a > 1e-3f && a < 50.0f) ? 1 : 0;
    __syncthreads();
    for (int o = 128; o > 0; o >>= 1) { if (t < o) cnt[t] += cnt[t + o]; __syncthreads(); }
    if (t == 0) *flag = (cnt[0] >= 205) ? 1 : 0;
}

__global__ __launch_bounds__(256)
void convert_embed(const void* __restrict__ in, bf16_t* __restrict__ out,
                   const int* __restrict__ flagp)
{
    int isbf = *flagp;
    long long i0 = ((long long)blockIdx.x * 256 + threadIdx.x) * 8;
    if (isbf) {
        *(s16x8*)(out + i0) = *(const s16x8*)((const bf16_t*)in + i0);
    } else {
        const float* f = (const float*)in;
        #pragma unroll
        for (int j = 0; j < 8; j++) out[i0 + j] = (bf16_t)f[i0 + j];
    }
}

// concat bq|bk|bv|bco -> cbias[3072] bf16
__global__ __launch_bounds__(256)
void concat_bias(const void* __restrict__ b0, const void* __restrict__ b1,
                 const void* __restrict__ b2, const void* __restrict__ b3,
                 bf16_t* __restrict__ out, const int* __restrict__ flagp)
{
    int isbf = *flagp;
    int t = blockIdx.x * 256 + threadIdx.x;   // < 3072
    int sel = t / 768, off = t - sel * 768;
    const void* src = (sel == 0) ? b0 : (sel == 1) ? b1 : (sel == 2) ? b2 : b3;
    out[t] = (bf16_t)rd_adapt(src, off, isbf);
}

// ---------------------------------------------------------------------------
// LDS-staged batched GEMM (m97 structure): 128x128 tile, BK=32, 4 waves.
// ---------------------------------------------------------------------------
__global__ __launch_bounds__(256)
void gemm_tile(const bf16_t* __restrict__ A, const bf16_t* __restrict__ Bt,
               bf16_t* __restrict__ C, const void* __restrict__ bias, long long biasOff,
               const bf16_t* __restrict__ emul, int lde, const int* __restrict__ flagp,
               int M, int N, int Kd, int lda, int ldb, int ldc,
               long long sAb, long long sAh, long long sBb, long long sBh,
               long long sCb, long long sCh, int nh, float scale, int act, int beta,
               int nlim)
{
    __shared__ bf16_t As[128 * 32];
    __shared__ bf16_t Bs[128 * 32];

    int isbf = flagp ? *flagp : 1;
    int z  = blockIdx.z;
    int zb = z / nh, zh = z - zb * nh;
    const bf16_t* Ap = A  + zb * sAb + zh * sAh;
    const bf16_t* Bp = Bt + zb * sBb + zh * sBh;
    bf16_t*       Cp = C  + zb * sCb + zh * sCh;
    const bf16_t* Ep = emul;

    int tid  = threadIdx.x;
    int wave = tid >> 6, lane = tid & 63;
    int wm = wave >> 1, wn = wave & 1;
    int row0 = blockIdx.x * 128;
    int col0 = blockIdx.y * 128;
    int lm = lane & 15;
    int kq = lane >> 4;

    int sr = tid >> 2;
    int sc = (tid & 3) * 8;
    const bf16_t* ga0 = Ap + (long long)(row0 + sr) * lda + sc;
    const bf16_t* ga1 = Ap + (long long)(row0 + 64 + sr) * lda + sc;
    int br0 = min(col0 + sr, nlim);
    int br1 = min(col0 + 64 + sr, nlim);
    const bf16_t* gb0 = Bp + (long long)br0 * ldb + sc;
    const bf16_t* gb1 = Bp + (long long)br1 * ldb + sc;
    bf16_t* la0 = As + wave * 512;
    bf16_t* la1 = As + 2048 + wave * 512;
    bf16_t* lb0 = Bs + wave * 512;
    bf16_t* lb1 = Bs + 2048 + wave * 512;

    f32x4 acc[4][4] = {};

    for (int k0 = 0; k0 < Kd; k0 += 32) {
        gl2lds16(ga0 + k0, la0);
        gl2lds16(ga1 + k0, la1);
        gl2lds16(gb0 + k0, lb0);
        gl2lds16(gb1 + k0, lb1);
        __syncthreads();

        s16x8 af[4], bfr[4];
        #pragma unroll
        for (int i = 0; i < 4; i++)
            af[i] = *(const s16x8*)(As + (wm * 64 + i * 16 + lm) * 32 + kq * 8);
        #pragma unroll
        for (int j = 0; j < 4; j++)
            bfr[j] = *(const s16x8*)(Bs + (wn * 64 + j * 16 + lm) * 32 + kq * 8);
        #pragma unroll
        for (int i = 0; i < 4; i++)
            #pragma unroll
            for (int j = 0; j < 4; j++)
                acc[i][j] = __builtin_amdgcn_mfma_f32_16x16x32_bf16(af[i], bfr[j], acc[i][j], 0, 0, 0);
        __syncthreads();
    }

    #pragma unroll
    for (int j = 0; j < 4; j++) {
        int gcol = col0 + wn * 64 + j * 16 + lm;
        if (gcol >= N) continue;
        float bv = bias ? rd_adapt(bias, biasOff + gcol, isbf) : 0.0f;
        #pragma unroll
        for (int i = 0; i < 4; i++) {
            int grow0 = row0 + wm * 64 + i * 16 + kq * 4;
            #pragma unroll
            for (int r = 0; r < 4; r++) {
                float v = acc[i][j][r] * scale + bv;
                long long ci = (long long)(grow0 + r) * ldc + gcol;
                if (beta) v += (float)Cp[ci];
                if (Ep) v *= (float)Ep[(long long)(grow0 + r) * lde + gcol];
                if (act) v = 0.5f * v * (1.0f + erff(v * 0.70710678118654752f));
                Cp[ci] = (bf16_t)v;
            }
        }
    }
}

// ---------------------------------------------------------------------------
// Fused flash attention. grid = (64 bh, 8 q-tiles), block = 256.
// bh fastest -> XCD = bh%8 -> all q-tiles of one (b,h) share an XCD's L2.
// Q at qkv[...,h*96], K at qkv[...,768+h*96], row stride 3072. V^T from vT.
// ---------------------------------------------------------------------------
__global__ __launch_bounds__(256, 2)
void flash_attn(const bf16_t* __restrict__ qkv, const bf16_t* __restrict__ vT,
                bf16_t* __restrict__ ctxcat)
{
    const float ascale = 0.1020620726159658f;   // 1/sqrt(96)
    __shared__ bf16_t Pl[4 * 32 * 136];         // per-wave P[32][136] (pad 8)

    int bh = blockIdx.x;
    int b = bh >> 3, h = bh & 7;
    const bf16_t* Qp = qkv  + (long long)b * SS * 3072 + h * HDD;
    const bf16_t* Kp = qkv  + (long long)b * SS * 3072 + 768 + h * HDD;
    const bf16_t* Vt = vT   + (long long)b * AHH * SS + (long long)h * HDD * SS;
    bf16_t*       Op = ctxcat + (long long)b * SS * HH + h * HDD;

    int tid = threadIdx.x, wave = tid >> 6, lane = tid & 63;
    int lm = lane & 15, kq = lane >> 4;
    int q0 = blockIdx.y * 128 + wave * 32;
    bf16_t* Pw = Pl + wave * 32 * 136;

    // Q fragments: 2 m-tiles x 3 k-frags, resident
    s16x8 aq[2][3];
    #pragma unroll
    for (int i = 0; i < 2; i++)
        #pragma unroll
        for (int kf = 0; kf < 3; kf++)
            aq[i][kf] = *(const s16x8*)(Qp + (long long)(q0 + i * 16 + lm) * 3072 + kf * 32 + kq * 8);

    f32x4 Oacc[2][6] = {};
    float mrow[2][4], lrow[2][4];
    #pragma unroll
    for (int i = 0; i < 2; i++)
        #pragma unroll
        for (int r = 0; r < 4; r++) { mrow[i][r] = -1e30f; lrow[i][r] = 0.0f; }

    for (int kt = 0; kt < 8; kt++) {
        // ---- S = Q K^T (raw) ----
        f32x4 S[2][8] = {};
        #pragma unroll
        for (int j = 0; j < 8; j++) {
            s16x8 bk[3];
            #pragma unroll
            for (int kf = 0; kf < 3; kf++)
                bk[kf] = *(const s16x8*)(Kp + (long long)(kt * 128 + j * 16 + lm) * 3072 + kf * 32 + kq * 8);
            #pragma unroll
            for (int i = 0; i < 2; i++)
                #pragma unroll
                for (int kf = 0; kf < 3; kf++)
                    S[i][j] = __builtin_amdgcn_mfma_f32_16x16x32_bf16(aq[i][kf], bk[kf], S[i][j], 0, 0, 0);
        }

        // ---- online softmax ----
        float mnew[2][4];
        #pragma unroll
        for (int i = 0; i < 2; i++) {
            #pragma unroll
            for (int r = 0; r < 4; r++) {
                float mx = -1e30f;
                #pragma unroll
                for (int j = 0; j < 8; j++) mx = fmaxf(mx, S[i][j][r]);
                #pragma unroll
                for (int msk = 1; msk <= 8; msk <<= 1) mx = fmaxf(mx, __shfl_xor(mx, msk));
                mnew[i][r] = fmaxf(mrow[i][r], mx * ascale);
            }
        }
        #pragma unroll
        for (int i = 0; i < 2; i++) {
            #pragma unroll
            for (int r = 0; r < 4; r++) {
                float al = __expf(mrow[i][r] - mnew[i][r]);
                lrow[i][r] *= al;
                #pragma unroll
                for (int n = 0; n < 6; n++) Oacc[i][n][r] *= al;
                mrow[i][r] = mnew[i][r];
            }
        }
        float psum[2][4] = {};
        __syncthreads();
        #pragma unroll
        for (int i = 0; i < 2; i++) {
            #pragma unroll
            for (int j = 0; j < 8; j++) {
                #pragma unroll
                for (int r = 0; r < 4; r++) {
                    float p = __expf(S[i][j][r] * ascale - mnew[i][r]);
                    psum[i][r] += p;
                    Pw[(i * 16 + kq * 4 + r) * 136 + j * 16 + lm] = (bf16_t)p;
                }
            }
        }
        #pragma unroll
        for (int i = 0; i < 2; i++) {
            #pragma unroll
            for (int r = 0; r < 4; r++) {
                float t = psum[i][r];
                #pragma unroll
                for (int msk = 1; msk <= 8; msk <<= 1) t += __shfl_xor(t, msk);
                lrow[i][r] += t;
            }
        }
        __syncthreads();

        // ---- O += P V ----
        s16x8 ap[2][4];
        #pragma unroll
        for (int i = 0; i < 2; i++)
            #pragma unroll
            for (int kf = 0; kf < 4; kf++)
                ap[i][kf] = *(const s16x8*)(Pw + (i * 16 + lm) * 136 + kf * 32 + kq * 8);
        #pragma unroll
        for (int n = 0; n < 6; n++) {
            s16x8 bv[4];
            #pragma unroll
            for (int kf = 0; kf < 4; kf++)
                bv[kf] = *(const s16x8*)(Vt + (long long)(n * 16 + lm) * SS + kt * 128 + kf * 32 + kq * 8);
            #pragma unroll
            for (int i = 0; i < 2; i++)
                #pragma unroll
                for (int kf = 0; kf < 4; kf++)
                    Oacc[i][n] = __builtin_amdgcn_mfma_f32_16x16x32_bf16(ap[i][kf], bv[kf], Oacc[i][n], 0, 0, 0);
        }
    }

    #pragma unroll
    for (int i = 0; i < 2; i++) {
        #pragma unroll
        for (int n = 0; n < 6; n++) {
            #pragma unroll
            for (int r = 0; r < 4; r++) {
                int row = q0 + i * 16 + kq * 4 + r;
                int col = n * 16 + lm;
                Op[(long long)row * HH + col] = (bf16_t)(Oacc[i][n][r] / lrow[i][r]);
            }
        }
    }
}

// ---------------------------------------------------------------------------
// Adaptive tiled transpose with zero-padding beyond C columns.
// ---------------------------------------------------------------------------
__global__ __launch_bounds__(256)
void transpose_pad(const void* __restrict__ in, bf16_t* __restrict__ out,
                   int R, int C, int ldin, long long inOff,
                   long long sInB, long long sOutB, const int* __restrict__ flagp)
{
    __shared__ bf16_t t[32][33];
    int isbf = flagp ? *flagp : 1;
    int z = blockIdx.z;
    long long base = inOff + (long long)z * sInB;
    bf16_t* op = out + (long long)z * sOutB;
    int tx = threadIdx.x & 31, ty = threadIdx.x >> 5;
    int cb = blockIdx.x * 32, rb = blockIdx.y * 32;
    #pragma unroll
    for (int rr = ty; rr < 32; rr += 8) {
        int r = rb + rr, c = cb + tx;
        t[rr][tx] = (c < C) ? (bf16_t)rd_adapt(in, base + (long long)r * ldin + c, isbf)
                            : (bf16_t)0.0f;
    }
    __syncthreads();
    #pragma unroll
    for (int rr = ty; rr < 32; rr += 8) {
        int c = cb + rr;
        op[(long long)c * R + rb + tx] = t[tx][rr];
    }
}

// depthwise conv k=7, 'same' padding along S
__global__ __launch_bounds__(256)
void dconv_kernel(const bf16_t* __restrict__ ebuf, const void* __restrict__ dw,
                  bf16_t* __restrict__ out, const int* __restrict__ flagp)
{
    int isbf = *flagp;
    long long i = (long long)blockIdx.x * 256 + threadIdx.x;   // < B*S*H
    int c = (int)(i % HH);
    long long bs = i / HH;
    int s = (int)(bs % SS);
    float acc = 0.0f;
    #pragma unroll
    for (int k = 0; k < 7; k++) {
        int ss = s + k - 3;
        if (ss >= 0 && ss < SS)
            acc += (float)ebuf[(bs + (k - 3)) * HH + c] * rd_adapt(dw, c * 7 + k, isbf);
    }
    out[i] = (bf16_t)acc;
}

// ck softmax over k=7 per (b,s,h)
__global__ __launch_bounds__(256)
void ck_softmax(const bf16_t* __restrict__ ck, float* __restrict__ ckp)
{
    int i = blockIdx.x * 256 + threadIdx.x;   // < B*S*NH
    if (i >= BB * SS * NHH) return;
    int h = i % NHH;
    long long bs = i / NHH;
    const bf16_t* src = ck + bs * 64 + h * 7;
    float v[7], mx = -1e30f;
    #pragma unroll
    for (int k = 0; k < 7; k++) { v[k] = (float)src[k]; mx = fmaxf(mx, v[k]); }
    float sum = 0.0f;
    #pragma unroll
    for (int k = 0; k < 7; k++) { v[k] = expf(v[k] - mx); sum += v[k]; }
    float inv = 1.0f / sum;
    float* dst = ckp + bs * 56 + h * 7;
    #pragma unroll
    for (int k = 0; k < 7; k++) dst[k] = v[k] * inv;
}

// conv_out -> right half (cols 768..1535) of ctxcat; co has row stride ldco
__global__ __launch_bounds__(256)
void conv_out_kernel(const bf16_t* __restrict__ co, int ldco,
                     const float* __restrict__ ckp, bf16_t* __restrict__ ctxcat)
{
    long long i = (long long)blockIdx.x * 256 + threadIdx.x;   // < B*S*AH
    int hd = (int)(i % AHH);
    long long bs = i / AHH;
    int s = (int)(bs % SS);
    int h = hd / HDD;
    const float* w = ckp + bs * 56 + h * 7;
    float acc = 0.0f;
    #pragma unroll
    for (int k = 0; k < 7; k++) {
        int ss = s + k - 3;
        if (ss >= 0 && ss < SS)
            acc += (float)co[(bs + (k - 3)) * ldco + hd] * w[k];
    }
    ctxcat[bs * HH + AHH + hd] = (bf16_t)acc;
}

// LayerNorm over 1536 of (y + res)
__global__ __launch_bounds__(256)
void ln_kernel(const bf16_t* __restrict__ y, const bf16_t* __restrict__ res,
               const void* __restrict__ g, const void* __restrict__ bta,
               bf16_t* __restrict__ outb, const int* __restrict__ flagp)
{
    int isbf = *flagp;
    long long row = blockIdx.x;
    const bf16_t* yp = y + row * HH;
    const bf16_t* rp = res + row * HH;
    int tid = threadIdx.x;
    float x[6], s = 0.0f, s2 = 0.0f;
    #pragma unroll
    for (int i = 0; i < 6; i++) {
        int c = tid + i * 256;
        float v = (float)yp[c] + (float)rp[c];
        x[i] = v; s += v; s2 += v * v;
    }
    __shared__ float sa[256], sb[256];
    sa[tid] = s; sb[tid] = s2; __syncthreads();
    for (int o = 128; o > 0; o >>= 1) {
        if (tid < o) { sa[tid] += sa[tid + o]; sb[tid] += sb[tid + o]; }
        __syncthreads();
    }
    float mean = sa[0] * (1.0f / HH);
    float var  = sb[0] * (1.0f / HH) - mean * mean;
    float inv  = rsqrtf(var + 1e-12f);
    #pragma unroll
    for (int i = 0; i < 6; i++) {
        int c = tid + i * 256;
        float v = (x[i] - mean) * inv * rd_adapt(g, c, isbf) + rd_adapt(bta, c, isbf);
        outb[row * HH + c] = (bf16_t)v;
    }
}

// two-phase maxpool
__global__ __launch_bounds__(256)
void maxpool_p1(const bf16_t* __restrict__ lo, float* __restrict__ part)
{
    int sc = blockIdx.x, b = blockIdx.y;       // 32 chunks x 8 batches
    int tid = threadIdx.x;
    const bf16_t* p = lo + ((long long)b * SS + sc * 32) * HH;
    float m[6];
    #pragma unroll
    for (int k = 0; k < 6; k++) m[k] = -1e30f;
    for (int r = 0; r < 32; r++)
        #pragma unroll
        for (int k = 0; k < 6; k++)
            m[k] = fmaxf(m[k], (float)p[(long long)r * HH + k * 256 + tid]);
    #pragma unroll
    for (int k = 0; k < 6; k++)
        part[((long long)b * 32 + sc) * HH + k * 256 + tid] = m[k];
}

__global__ __launch_bounds__(256)
void maxpool_p2(const float* __restrict__ part, float* __restrict__ pooled)
{
    int i = blockIdx.x * 256 + threadIdx.x;    // < B*H
    if (i >= BB * HH) return;
    int b = i / HH, c = i % HH;
    float m = -1e30f;
    for (int ch = 0; ch < 32; ch++) m = fmaxf(m, part[((long long)b * 32 + ch) * HH + c]);
    pooled[i] = m;
}

// logits[b] = pooled[b,:] . wd + bd
__global__ __launch_bounds__(256)
void decoder_kernel(const float* __restrict__ pooled, const void* __restrict__ wd,
                    const void* __restrict__ bd, void* __restrict__ out,
                    const int* __restrict__ flagp)
{
    int isbf = *flagp;
    int b = blockIdx.x;
    int tid = threadIdx.x;
    float s = 0.0f;
    #pragma unroll
    for (int i = 0; i < 6; i++) {
        int c = tid + i * 256;
        s += pooled[b * HH + c] * rd_adapt(wd, c, isbf);
    }
    __shared__ float sa[256];
    sa[tid] = s; __syncthreads();
    for (int o = 128; o > 0; o >>= 1) { if (tid < o) sa[tid] += sa[tid + o]; __syncthreads(); }
    if (tid == 0) {
        float r = sa[0] + rd_adapt(bd, 0, isbf);
        if (isbf) ((bf16_t*)out)[b] = (bf16_t)r;
        else      ((float*)out)[b]  = r;
    }
}

// ---------------------------------------------------------------------------
extern "C" void kernel_launch(void* const* d_in, const int* in_sizes, int n_in,
                              void* d_out, int out_size, void* d_ws, size_t ws_size,
                              hipStream_t stream)
{
    const void* embed = d_in[0];
    const void* wq  = d_in[1];  const void* bq  = d_in[2];
    const void* wk  = d_in[3];  const void* bk  = d_in[4];
    const void* wv  = d_in[5];  const void* bv  = d_in[6];
    const void* dw  = d_in[7];  const void* pw  = d_in[8];  const void* sep_b = d_in[9];
    const void* wck = d_in[10]; const void* bck = d_in[11];
    const void* wco = d_in[12]; const void* bco = d_in[13];
    const void* wso = d_in[14]; const void* bso = d_in[15];
    const void* ln1g = d_in[16]; const void* ln1b = d_in[17];
    const void* wi  = d_in[18]; const void* bi  = d_in[19];
    const void* wo  = d_in[20]; const void* bo  = d_in[21];
    const void* ln2g = d_in[22]; const void* ln2b = d_in[23];
    const void* wd  = d_in[24]; const void* bd  = d_in[25];
    (void)ws_size; (void)in_sizes; (void)n_in; (void)out_size;

    // ---- arena (143.2 MB), lifetime-aliased ----
    char* ws = (char*)d_ws;
    char* A  = ws;                          // 50.33 MB: qkvco -> ybuf/interb/lout
    char* B  = ws + 50331648;               // 25.17 MB: wT_all -> dconvb -> ckb/ckp -> vT -> wiT/woT
    char* C_ = ws + 75497472;               // 12.58 MB: sepb -> mpart
    char* D  = ws + 88080384;               // 25.17 MB: ctxcat -> attn
    char* E  = ws + 113246208;              // 25.17 MB: ebuf -> y2
    char* F  = ws + 138412032;              //  4.72 MB: wT (pw / wck / wso)
    char* XP = ws + 143130624;              //  flag + pooled + cbias

    bf16_t* qkvco  = (bf16_t*)A;                    // [8192,3072]
    bf16_t* ybuf   = (bf16_t*)A;                    // [8192,1536] (after flash)
    bf16_t* interb = (bf16_t*)A;                    // [8192,3072] (after ln1)
    bf16_t* lout   = (bf16_t*)A;                    // [8192,1536] (after wo)
    bf16_t* wT_all = (bf16_t*)B;                    // [3072,1536] (merged gemm)
    bf16_t* dconvb = (bf16_t*)B;                    // [8192,1536] (after merged)
    bf16_t* ckb    = (bf16_t*)B;                    // [8192,64]   (after sep)
    float*  ckp    = (float*)(B + 1310720);         // [8192,56] f32
    bf16_t* vT     = (bf16_t*)B;                    // [8,768,1024] (after conv_out)
    bf16_t* wfT    = (bf16_t*)B;                    // wiT [3072,1536] / woT [1536,3072]
    bf16_t* sepb   = (bf16_t*)C_;                   // [8192,768]
    float*  mpart  = (float*)C_;                    // [8,32,1536] f32
    bf16_t* ctxcat = (bf16_t*)D;                    // [8192,1536]
    bf16_t* attn   = (bf16_t*)D;                    // [8192,1536]
    bf16_t* ebuf   = (bf16_t*)E;                    // [8192,1536]
    bf16_t* y2     = (bf16_t*)E;                    // [8192,1536]
    bf16_t* wT     = (bf16_t*)F;
    int*    flag   = (int*)XP;
    float*  pooled = (float*)(XP + 256);            // [8,1536] f32
    bf16_t* cbias  = (bf16_t*)(XP + 256 + 49152);   // [3072]

    dim3 blk(256);

    auto gemm = [&](const bf16_t* Ai, const bf16_t* Bt, bf16_t* Ci, const void* bias,
                    long long biasOff, const bf16_t* emul, int lde, const int* fl,
                    int M, int N, int Kd, int lda, int ldb, int ldc,
                    float scale, int act, int beta, int nlim) {
        dim3 g(M / 128, (N + 127) / 128, 1);
        gemm_tile<<<g, blk, 0, stream>>>(Ai, Bt, Ci, bias, biasOff, emul, lde, fl,
                                         M, N, Kd, lda, ldb, ldc,
                                         0, 0, 0, 0, 0, 0, 1, scale, act, beta, nlim);
    };
    auto transpose = [&](const void* in, bf16_t* out, int R, int Cc, int Cpad, int ldin,
                         long long inOff, int batch, long long sInB, long long sOutB,
                         const int* fl) {
        dim3 g(Cpad / 32, R / 32, batch);
        transpose_pad<<<g, blk, 0, stream>>>(in, out, R, Cc, ldin, inOff, sInB, sOutB, fl);
    };

    // --- dtype probe + embed conversion ---
    detect_kernel<<<dim3(1), blk, 0, stream>>>(embed, flag);
    convert_embed<<<dim3(6144), blk, 0, stream>>>(embed, ebuf, flag);

    // --- merged Q|K|V|co projection: [8192,1536] x [3072,1536]^T -> [8192,3072] ---
    transpose(wq,  wT_all + 0ll * 768 * 1536, 1536, 768, 768, 768, 0, 1, 0, 0, flag);
    transpose(wk,  wT_all + 1ll * 768 * 1536, 1536, 768, 768, 768, 0, 1, 0, 0, flag);
    transpose(wv,  wT_all + 2ll * 768 * 1536, 1536, 768, 768, 768, 0, 1, 0, 0, flag);
    transpose(wco, wT_all + 3ll * 768 * 1536, 1536, 768, 768, 768, 0, 1, 0, 0, flag);
    concat_bias<<<dim3(12), blk, 0, stream>>>(bq, bk, bv, bco, cbias, flag);
    gemm(ebuf, wT_all, qkvco, cbias, 0, nullptr, 0, nullptr,
         8192, 3072, 1536, HH, HH, 3072, 1.0f, 0, 0, 3071);

    // --- separable conv: depthwise, then pointwise fused with *q ---
    dconv_kernel<<<dim3((BB * SS * HH) / 256), blk, 0, stream>>>(ebuf, dw, dconvb, flag);
    transpose(pw, wT, 1536, 768, 768, 768, 0, 1, 0, 0, flag);
    gemm(dconvb, wT, sepb, sep_b, 0, qkvco, 3072, flag,
         8192, 768, 1536, HH, HH, AHH, 1.0f, 0, 0, 767);

    // --- span conv kernels (wckT padded to 128 rows) ---
    transpose(wck, wT, 768, 56, 128, 56, 0, 1, 0, 0, flag);
    gemm(sepb, wT, ckb, bck, 0, nullptr, 0, flag,
         8192, 56, 768, AHH, AHH, 64, 1.0f, 0, 0, 127);
    ck_softmax<<<dim3((BB * SS * NHH) / 256), blk, 0, stream>>>(ckb, ckp);
    conv_out_kernel<<<dim3((BB * SS * AHH) / 256), blk, 0, stream>>>(qkvco + 2304, 3072, ckp, ctxcat);

    // --- fused flash attention (XCD-local grid: bh fastest) ---
    transpose(qkvco, vT, 1024, 768, 768, 3072, 1536, 8, 1024ll * 3072, 768ll * 1024, nullptr);
    flash_attn<<<dim3(64, 8), blk, 0, stream>>>(qkvco, vT, ctxcat);

    // --- self output + LN1 ---
    transpose(wso, wT, 1536, 1536, 1536, 1536, 0, 1, 0, 0, flag);
    gemm(ctxcat, wT, ybuf, bso, 0, nullptr, 0, flag,
         8192, 1536, 1536, HH, HH, HH, 1.0f, 0, 0, 1535);
    ln_kernel<<<dim3(8192), blk, 0, stream>>>(ybuf, ebuf, ln1g, ln1b, attn, flag);

    // --- FFN full-width + LN2 ---
    transpose(wi, wfT, 1536, 3072, 3072, 3072, 0, 1, 0, 0, flag);      // wiT [3072,1536]
    gemm(attn, wfT, interb, bi, 0, nullptr, 0, flag,
         8192, 3072, 1536, HH, HH, IMM, 1.0f, 1, 0, 3071);
    transpose(wo, wfT, 3072, 1536, 1536, 1536, 0, 1, 0, 0, flag);      // woT [1536,3072]
    gemm(interb, wfT, y2, bo, 0, nullptr, 0, flag,
         8192, 1536, 3072, IMM, IMM, HH, 1.0f, 0, 0, 1535);
    ln_kernel<<<dim3(8192), blk, 0, stream>>>(y2, attn, ln2g, ln2b, lout, flag);

    // --- pool + decode (partials in dead sepb slot) ---
    maxpool_p1<<<dim3(32, 8), blk, 0, stream>>>(lout, mpart);
    maxpool_p2<<<dim3(48), blk, 0, stream>>>(mpart, pooled);
    decoder_kernel<<<dim3(BB), blk, 0, stream>>>(pooled, wd, bd, d_out, flag);
}

// Round 7
// 917.406 us; speedup vs baseline: 2.9026x; 1.0597x over previous
//
#include <hip/hip_runtime.h>

// ---------------------------------------------------------------------------
// ConvBERT layer forward, bf16 compute / fp32 accumulate.
// B=8 S=1024 H=1536 NH=8 HD=96 AH=768 K=7 IM=3072
// Round 7: gemm_tile BK=64 (two 128x32 half-tiles per stage -> half the
//          barrier count, 32 MFMA per sync pair) + fast tanh-GELU epilogue.
// ---------------------------------------------------------------------------

typedef __bf16 bf16_t;
typedef short s16x8 __attribute__((ext_vector_type(8)));   // 8 bf16 in 4 VGPRs
typedef float f32x4 __attribute__((ext_vector_type(4)));

#define BB  8
#define SS  1024
#define HH  1536
#define NHH 8
#define HDD 96
#define AHH 768
#define IMM 3072

__device__ __forceinline__ float rd_adapt(const void* p, long long i, int isbf) {
    return isbf ? (float)((const bf16_t*)p)[i] : ((const float*)p)[i];
}

// tanh-form GELU: max |diff| vs exact erf-GELU ~3e-3, far under bf16 budget
__device__ __forceinline__ float gelu_f(float v) {
    float u = v * (0.7978845608f + 0.0356774081f * v * v);
    float e = __expf(2.0f * u);
    float t = 1.0f - 2.0f / (e + 1.0f);
    return 0.5f * v * (1.0f + t);
}

// async global->LDS, 16B per lane; lds base must be wave-uniform
__device__ __forceinline__ void gl2lds16(const bf16_t* g, bf16_t* l) {
    __builtin_amdgcn_global_load_lds(
        (__attribute__((address_space(1))) const void*)g,
        (__attribute__((address_space(3))) void*)l, 16, 0, 0);
}

// ---------------------------------------------------------------------------
// dtype probe: bf16 vs fp32 inputs. flag=1 -> bf16.
// ---------------------------------------------------------------------------
__global__ __launch_bounds__(256)
void detect_kernel(const void* __restrict__ embed, int* __restrict__ flag)
{
    __shared__ int cnt[256];
    int t = threadIdx.x;
    float x = (float)((const bf16_t*)embed)[t];
    float a = fabsf(x);
    cnt[t] = (a > 1e-3f && a < 50.0f) ? 1 : 0;
    __syncthreads();
    for (int o = 128; o > 0; o >>= 1) { if (t < o) cnt[t] += cnt[t + o]; __syncthreads(); }
    if (t == 0) *flag = (cnt[0] >= 205) ? 1 : 0;
}

__global__ __launch_bounds__(256)
void convert_embed(const void* __restrict__ in, bf16_t* __restrict__ out,
                   const int* __restrict__ flagp)
{
    int isbf = *flagp;
    long long i0 = ((long long)blockIdx.x * 256 + threadIdx.x) * 8;
    if (isbf) {
        *(s16x8*)(out + i0) = *(const s16x8*)((const bf16_t*)in + i0);
    } else {
        const float* f = (const float*)in;
        #pragma unroll
        for (int j = 0; j < 8; j++) out[i0 + j] = (bf16_t)f[i0 + j];
    }
}

// concat bq|bk|bv|bco -> cbias[3072] bf16
__global__ __launch_bounds__(256)
void concat_bias(const void* __restrict__ b0, const void* __restrict__ b1,
                 const void* __restrict__ b2, const void* __restrict__ b3,
                 bf16_t* __restrict__ out, const int* __restrict__ flagp)
{
    int isbf = *flagp;
    int t = blockIdx.x * 256 + threadIdx.x;   // < 3072
    int sel = t / 768, off = t - sel * 768;
    const void* src = (sel == 0) ? b0 : (sel == 1) ? b1 : (sel == 2) ? b2 : b3;
    out[t] = (bf16_t)rd_adapt(src, off, isbf);
}

// ---------------------------------------------------------------------------
// LDS-staged GEMM: 128x128 tile, BK=64 staged as two 128x32 half-tiles,
// block = 256 (4 waves), wave = 64x64 = 4x4 mfma 16x16x32, 32 MFMA/barrier.
// C = post(scale*A@Bt^T + bias [+C]); Kd % 64 == 0, M % 128 == 0.
// ---------------------------------------------------------------------------
__global__ __launch_bounds__(256)
void gemm_tile(const bf16_t* __restrict__ A, const bf16_t* __restrict__ Bt,
               bf16_t* __restrict__ C, const void* __restrict__ bias, long long biasOff,
               const bf16_t* __restrict__ emul, int lde, const int* __restrict__ flagp,
               int M, int N, int Kd, int lda, int ldb, int ldc,
               float scale, int act, int beta, int nlim)
{
    __shared__ bf16_t Sm[16384];   // As: [2][128][32] at 0; Bs: [2][128][32] at 8192

    int isbf = flagp ? *flagp : 1;
    int tid  = threadIdx.x;
    int wave = tid >> 6, lane = tid & 63;
    int wm = wave >> 1, wn = wave & 1;
    int row0 = blockIdx.x * 128;
    int col0 = blockIdx.y * 128;
    int lm = lane & 15;
    int kq = lane >> 4;

    int sr = tid >> 2;            // 0..63
    int sc = (tid & 3) * 8;       // 0,8,16,24
    const bf16_t* ga0 = A + (long long)(row0 + sr) * lda + sc;
    const bf16_t* ga1 = A + (long long)(row0 + 64 + sr) * lda + sc;
    int br0 = min(col0 + sr, nlim);
    int br1 = min(col0 + 64 + sr, nlim);
    const bf16_t* gb0 = Bt + (long long)br0 * ldb + sc;
    const bf16_t* gb1 = Bt + (long long)br1 * ldb + sc;
    bf16_t* lw = Sm + wave * 512;   // wave-uniform staging base

    f32x4 acc[4][4] = {};

    for (int k0 = 0; k0 < Kd; k0 += 64) {
        #pragma unroll
        for (int h = 0; h < 2; h++) {
            int kh = k0 + h * 32;
            gl2lds16(ga0 + kh, lw + h * 4096);
            gl2lds16(ga1 + kh, lw + h * 4096 + 2048);
            gl2lds16(gb0 + kh, lw + 8192 + h * 4096);
            gl2lds16(gb1 + kh, lw + 8192 + h * 4096 + 2048);
        }
        __syncthreads();

        s16x8 af[2][4], bfr[2][4];
        #pragma unroll
        for (int h = 0; h < 2; h++) {
            #pragma unroll
            for (int i = 0; i < 4; i++)
                af[h][i] = *(const s16x8*)(Sm + h * 4096 + (wm * 64 + i * 16 + lm) * 32 + kq * 8);
            #pragma unroll
            for (int j = 0; j < 4; j++)
                bfr[h][j] = *(const s16x8*)(Sm + 8192 + h * 4096 + (wn * 64 + j * 16 + lm) * 32 + kq * 8);
        }
        #pragma unroll
        for (int i = 0; i < 4; i++)
            #pragma unroll
            for (int j = 0; j < 4; j++) {
                acc[i][j] = __builtin_amdgcn_mfma_f32_16x16x32_bf16(af[0][i], bfr[0][j], acc[i][j], 0, 0, 0);
                acc[i][j] = __builtin_amdgcn_mfma_f32_16x16x32_bf16(af[1][i], bfr[1][j], acc[i][j], 0, 0, 0);
            }
        __syncthreads();
    }

    // epilogue: D row = kq*4 + r, col = lm (m89/m91-verified)
    #pragma unroll
    for (int j = 0; j < 4; j++) {
        int gcol = col0 + wn * 64 + j * 16 + lm;
        if (gcol >= N) continue;
        float bv = bias ? rd_adapt(bias, biasOff + gcol, isbf) : 0.0f;
        #pragma unroll
        for (int i = 0; i < 4; i++) {
            int grow0 = row0 + wm * 64 + i * 16 + kq * 4;
            #pragma unroll
            for (int r = 0; r < 4; r++) {
                float v = acc[i][j][r] * scale + bv;
                long long ci = (long long)(grow0 + r) * ldc + gcol;
                if (beta) v += (float)C[ci];
                if (emul) v *= (float)emul[(long long)(grow0 + r) * lde + gcol];
                if (act) v = gelu_f(v);
                C[ci] = (bf16_t)v;
            }
        }
    }
}

// ---------------------------------------------------------------------------
// Fused flash attention. grid = (64 bh, 8 q-tiles), block = 256.
// bh fastest -> XCD = bh%8 -> all q-tiles of one (b,h) share an XCD's L2.
// ---------------------------------------------------------------------------
__global__ __launch_bounds__(256, 2)
void flash_attn(const bf16_t* __restrict__ qkv, const bf16_t* __restrict__ vT,
                bf16_t* __restrict__ ctxcat)
{
    const float ascale = 0.1020620726159658f;   // 1/sqrt(96)
    __shared__ bf16_t Pl[4 * 32 * 136];         // per-wave P[32][136] (pad 8)

    int bh = blockIdx.x;
    int b = bh >> 3, h = bh & 7;
    const bf16_t* Qp = qkv  + (long long)b * SS * 3072 + h * HDD;
    const bf16_t* Kp = qkv  + (long long)b * SS * 3072 + 768 + h * HDD;
    const bf16_t* Vt = vT   + (long long)b * AHH * SS + (long long)h * HDD * SS;
    bf16_t*       Op = ctxcat + (long long)b * SS * HH + h * HDD;

    int tid = threadIdx.x, wave = tid >> 6, lane = tid & 63;
    int lm = lane & 15, kq = lane >> 4;
    int q0 = blockIdx.y * 128 + wave * 32;
    bf16_t* Pw = Pl + wave * 32 * 136;

    s16x8 aq[2][3];
    #pragma unroll
    for (int i = 0; i < 2; i++)
        #pragma unroll
        for (int kf = 0; kf < 3; kf++)
            aq[i][kf] = *(const s16x8*)(Qp + (long long)(q0 + i * 16 + lm) * 3072 + kf * 32 + kq * 8);

    f32x4 Oacc[2][6] = {};
    float mrow[2][4], lrow[2][4];
    #pragma unroll
    for (int i = 0; i < 2; i++)
        #pragma unroll
        for (int r = 0; r < 4; r++) { mrow[i][r] = -1e30f; lrow[i][r] = 0.0f; }

    for (int kt = 0; kt < 8; kt++) {
        f32x4 S[2][8] = {};
        #pragma unroll
        for (int j = 0; j < 8; j++) {
            s16x8 bk[3];
            #pragma unroll
            for (int kf = 0; kf < 3; kf++)
                bk[kf] = *(const s16x8*)(Kp + (long long)(kt * 128 + j * 16 + lm) * 3072 + kf * 32 + kq * 8);
            #pragma unroll
            for (int i = 0; i < 2; i++)
                #pragma unroll
                for (int kf = 0; kf < 3; kf++)
                    S[i][j] = __builtin_amdgcn_mfma_f32_16x16x32_bf16(aq[i][kf], bk[kf], S[i][j], 0, 0, 0);
        }

        float mnew[2][4];
        #pragma unroll
        for (int i = 0; i < 2; i++) {
            #pragma unroll
            for (int r = 0; r < 4; r++) {
                float mx = -1e30f;
                #pragma unroll
                for (int j = 0; j < 8; j++) mx = fmaxf(mx, S[i][j][r]);
                #pragma unroll
                for (int msk = 1; msk <= 8; msk <<= 1) mx = fmaxf(mx, __shfl_xor(mx, msk));
                mnew[i][r] = fmaxf(mrow[i][r], mx * ascale);
            }
        }
        #pragma unroll
        for (int i = 0; i < 2; i++) {
            #pragma unroll
            for (int r = 0; r < 4; r++) {
                float al = __expf(mrow[i][r] - mnew[i][r]);
                lrow[i][r] *= al;
                #pragma unroll
                for (int n = 0; n < 6; n++) Oacc[i][n][r] *= al;
                mrow[i][r] = mnew[i][r];
            }
        }
        float psum[2][4] = {};
        __syncthreads();
        #pragma unroll
        for (int i = 0; i < 2; i++) {
            #pragma unroll
            for (int j = 0; j < 8; j++) {
                #pragma unroll
                for (int r = 0; r < 4; r++) {
                    float p = __expf(S[i][j][r] * ascale - mnew[i][r]);
                    psum[i][r] += p;
                    Pw[(i * 16 + kq * 4 + r) * 136 + j * 16 + lm] = (bf16_t)p;
                }
            }
        }
        #pragma unroll
        for (int i = 0; i < 2; i++) {
            #pragma unroll
            for (int r = 0; r < 4; r++) {
                float t = psum[i][r];
                #pragma unroll
                for (int msk = 1; msk <= 8; msk <<= 1) t += __shfl_xor(t, msk);
                lrow[i][r] += t;
            }
        }
        __syncthreads();

        s16x8 ap[2][4];
        #pragma unroll
        for (int i = 0; i < 2; i++)
            #pragma unroll
            for (int kf = 0; kf < 4; kf++)
                ap[i][kf] = *(const s16x8*)(Pw + (i * 16 + lm) * 136 + kf * 32 + kq * 8);
        #pragma unroll
        for (int n = 0; n < 6; n++) {
            s16x8 bv[4];
            #pragma unroll
            for (int kf = 0; kf < 4; kf++)
                bv[kf] = *(const s16x8*)(Vt + (long long)(n * 16 + lm) * SS + kt * 128 + kf * 32 + kq * 8);
            #pragma unroll
            for (int i = 0; i < 2; i++)
                #pragma unroll
                for (int kf = 0; kf < 4; kf++)
                    Oacc[i][n] = __builtin_amdgcn_mfma_f32_16x16x32_bf16(ap[i][kf], bv[kf], Oacc[i][n], 0, 0, 0);
        }
    }

    #pragma unroll
    for (int i = 0; i < 2; i++) {
        #pragma unroll
        for (int n = 0; n < 6; n++) {
            #pragma unroll
            for (int r = 0; r < 4; r++) {
                int row = q0 + i * 16 + kq * 4 + r;
                int col = n * 16 + lm;
                Op[(long long)row * HH + col] = (bf16_t)(Oacc[i][n][r] / lrow[i][r]);
            }
        }
    }
}

// ---------------------------------------------------------------------------
// Adaptive tiled transpose with zero-padding beyond C columns.
// ---------------------------------------------------------------------------
__global__ __launch_bounds__(256)
void transpose_pad(const void* __restrict__ in, bf16_t* __restrict__ out,
                   int R, int C, int ldin, long long inOff,
                   long long sInB, long long sOutB, const int* __restrict__ flagp)
{
    __shared__ bf16_t t[32][33];
    int isbf = flagp ? *flagp : 1;
    int z = blockIdx.z;
    long long base = inOff + (long long)z * sInB;
    bf16_t* op = out + (long long)z * sOutB;
    int tx = threadIdx.x & 31, ty = threadIdx.x >> 5;
    int cb = blockIdx.x * 32, rb = blockIdx.y * 32;
    #pragma unroll
    for (int rr = ty; rr < 32; rr += 8) {
        int r = rb + rr, c = cb + tx;
        t[rr][tx] = (c < C) ? (bf16_t)rd_adapt(in, base + (long long)r * ldin + c, isbf)
                            : (bf16_t)0.0f;
    }
    __syncthreads();
    #pragma unroll
    for (int rr = ty; rr < 32; rr += 8) {
        int c = cb + rr;
        op[(long long)c * R + rb + tx] = t[tx][rr];
    }
}

// depthwise conv k=7, 'same' padding along S
__global__ __launch_bounds__(256)
void dconv_kernel(const bf16_t* __restrict__ ebuf, const void* __restrict__ dw,
                  bf16_t* __restrict__ out, const int* __restrict__ flagp)
{
    int isbf = *flagp;
    long long i = (long long)blockIdx.x * 256 + threadIdx.x;   // < B*S*H
    int c = (int)(i % HH);
    long long bs = i / HH;
    int s = (int)(bs % SS);
    float acc = 0.0f;
    #pragma unroll
    for (int k = 0; k < 7; k++) {
        int ss = s + k - 3;
        if (ss >= 0 && ss < SS)
            acc += (float)ebuf[(bs + (k - 3)) * HH + c] * rd_adapt(dw, c * 7 + k, isbf);
    }
    out[i] = (bf16_t)acc;
}

// ck softmax over k=7 per (b,s,h)
__global__ __launch_bounds__(256)
void ck_softmax(const bf16_t* __restrict__ ck, float* __restrict__ ckp)
{
    int i = blockIdx.x * 256 + threadIdx.x;   // < B*S*NH
    if (i >= BB * SS * NHH) return;
    int h = i % NHH;
    long long bs = i / NHH;
    const bf16_t* src = ck + bs * 64 + h * 7;
    float v[7], mx = -1e30f;
    #pragma unroll
    for (int k = 0; k < 7; k++) { v[k] = (float)src[k]; mx = fmaxf(mx, v[k]); }
    float sum = 0.0f;
    #pragma unroll
    for (int k = 0; k < 7; k++) { v[k] = expf(v[k] - mx); sum += v[k]; }
    float inv = 1.0f / sum;
    float* dst = ckp + bs * 56 + h * 7;
    #pragma unroll
    for (int k = 0; k < 7; k++) dst[k] = v[k] * inv;
}

// conv_out -> right half (cols 768..1535) of ctxcat; co has row stride ldco
__global__ __launch_bounds__(256)
void conv_out_kernel(const bf16_t* __restrict__ co, int ldco,
                     const float* __restrict__ ckp, bf16_t* __restrict__ ctxcat)
{
    long long i = (long long)blockIdx.x * 256 + threadIdx.x;   // < B*S*AH
    int hd = (int)(i % AHH);
    long long bs = i / AHH;
    int s = (int)(bs % SS);
    int h = hd / HDD;
    const float* w = ckp + bs * 56 + h * 7;
    float acc = 0.0f;
    #pragma unroll
    for (int k = 0; k < 7; k++) {
        int ss = s + k - 3;
        if (ss >= 0 && ss < SS)
            acc += (float)co[(bs + (k - 3)) * ldco + hd] * w[k];
    }
    ctxcat[bs * HH + AHH + hd] = (bf16_t)acc;
}

// LayerNorm over 1536 of (y + res)
__global__ __launch_bounds__(256)
void ln_kernel(const bf16_t* __restrict__ y, const bf16_t* __restrict__ res,
               const void* __restrict__ g, const void* __restrict__ bta,
               bf16_t* __restrict__ outb, const int* __restrict__ flagp)
{
    int isbf = *flagp;
    long long row = blockIdx.x;
    const bf16_t* yp = y + row * HH;
    const bf16_t* rp = res + row * HH;
    int tid = threadIdx.x;
    float x[6], s = 0.0f, s2 = 0.0f;
    #pragma unroll
    for (int i = 0; i < 6; i++) {
        int c = tid + i * 256;
        float v = (float)yp[c] + (float)rp[c];
        x[i] = v; s += v; s2 += v * v;
    }
    __shared__ float sa[256], sb[256];
    sa[tid] = s; sb[tid] = s2; __syncthreads();
    for (int o = 128; o > 0; o >>= 1) {
        if (tid < o) { sa[tid] += sa[tid + o]; sb[tid] += sb[tid + o]; }
        __syncthreads();
    }
    float mean = sa[0] * (1.0f / HH);
    float var  = sb[0] * (1.0f / HH) - mean * mean;
    float inv  = rsqrtf(var + 1e-12f);
    #pragma unroll
    for (int i = 0; i < 6; i++) {
        int c = tid + i * 256;
        float v = (x[i] - mean) * inv * rd_adapt(g, c, isbf) + rd_adapt(bta, c, isbf);
        outb[row * HH + c] = (bf16_t)v;
    }
}

// two-phase maxpool
__global__ __launch_bounds__(256)
void maxpool_p1(const bf16_t* __restrict__ lo, float* __restrict__ part)
{
    int sc = blockIdx.x, b = blockIdx.y;       // 32 chunks x 8 batches
    int tid = threadIdx.x;
    const bf16_t* p = lo + ((long long)b * SS + sc * 32) * HH;
    float m[6];
    #pragma unroll
    for (int k = 0; k < 6; k++) m[k] = -1e30f;
    for (int r = 0; r < 32; r++)
        #pragma unroll
        for (int k = 0; k < 6; k++)
            m[k] = fmaxf(m[k], (float)p[(long long)r * HH + k * 256 + tid]);
    #pragma unroll
    for (int k = 0; k < 6; k++)
        part[((long long)b * 32 + sc) * HH + k * 256 + tid] = m[k];
}

__global__ __launch_bounds__(256)
void maxpool_p2(const float* __restrict__ part, float* __restrict__ pooled)
{
    int i = blockIdx.x * 256 + threadIdx.x;    // < B*H
    if (i >= BB * HH) return;
    int b = i / HH, c = i % HH;
    float m = -1e30f;
    for (int ch = 0; ch < 32; ch++) m = fmaxf(m, part[((long long)b * 32 + ch) * HH + c]);
    pooled[i] = m;
}

// logits[b] = pooled[b,:] . wd + bd
__global__ __launch_bounds__(256)
void decoder_kernel(const float* __restrict__ pooled, const void* __restrict__ wd,
                    const void* __restrict__ bd, void* __restrict__ out,
                    const int* __restrict__ flagp)
{
    int isbf = *flagp;
    int b = blockIdx.x;
    int tid = threadIdx.x;
    float s = 0.0f;
    #pragma unroll
    for (int i = 0; i < 6; i++) {
        int c = tid + i * 256;
        s += pooled[b * HH + c] * rd_adapt(wd, c, isbf);
    }
    __shared__ float sa[256];
    sa[tid] = s; __syncthreads();
    for (int o = 128; o > 0; o >>= 1) { if (tid < o) sa[tid] += sa[tid + o]; __syncthreads(); }
    if (tid == 0) {
        float r = sa[0] + rd_adapt(bd, 0, isbf);
        if (isbf) ((bf16_t*)out)[b] = (bf16_t)r;
        else      ((float*)out)[b]  = r;
    }
}

// ---------------------------------------------------------------------------
extern "C" void kernel_launch(void* const* d_in, const int* in_sizes, int n_in,
                              void* d_out, int out_size, void* d_ws, size_t ws_size,
                              hipStream_t stream)
{
    const void* embed = d_in[0];
    const void* wq  = d_in[1];  const void* bq  = d_in[2];
    const void* wk  = d_in[3];  const void* bk  = d_in[4];
    const void* wv  = d_in[5];  const void* bv  = d_in[6];
    const void* dw  = d_in[7];  const void* pw  = d_in[8];  const void* sep_b = d_in[9];
    const void* wck = d_in[10]; const void* bck = d_in[11];
    const void* wco = d_in[12]; const void* bco = d_in[13];
    const void* wso = d_in[14]; const void* bso = d_in[15];
    const void* ln1g = d_in[16]; const void* ln1b = d_in[17];
    const void* wi  = d_in[18]; const void* bi  = d_in[19];
    const void* wo  = d_in[20]; const void* bo  = d_in[21];
    const void* ln2g = d_in[22]; const void* ln2b = d_in[23];
    const void* wd  = d_in[24]; const void* bd  = d_in[25];
    (void)ws_size; (void)in_sizes; (void)n_in; (void)out_size;

    // ---- arena (143.2 MB), lifetime-aliased (identical to round 6) ----
    char* ws = (char*)d_ws;
    char* A  = ws;                          // 50.33 MB: qkvco -> ybuf/interb/lout
    char* B  = ws + 50331648;               // 25.17 MB: wT_all -> dconvb -> ckb/ckp -> vT -> wiT/woT
    char* C_ = ws + 75497472;               // 12.58 MB: sepb -> mpart
    char* D  = ws + 88080384;               // 25.17 MB: ctxcat -> attn
    char* E  = ws + 113246208;              // 25.17 MB: ebuf -> y2
    char* F  = ws + 138412032;              //  4.72 MB: wT (pw / wck / wso)
    char* XP = ws + 143130624;              //  flag + pooled + cbias

    bf16_t* qkvco  = (bf16_t*)A;                    // [8192,3072]
    bf16_t* ybuf   = (bf16_t*)A;                    // [8192,1536] (after flash)
    bf16_t* interb = (bf16_t*)A;                    // [8192,3072] (after ln1)
    bf16_t* lout   = (bf16_t*)A;                    // [8192,1536] (after wo)
    bf16_t* wT_all = (bf16_t*)B;                    // [3072,1536] (merged gemm)
    bf16_t* dconvb = (bf16_t*)B;                    // [8192,1536] (after merged)
    bf16_t* ckb    = (bf16_t*)B;                    // [8192,64]   (after sep)
    float*  ckp    = (float*)(B + 1310720);         // [8192,56] f32
    bf16_t* vT     = (bf16_t*)B;                    // [8,768,1024] (after conv_out)
    bf16_t* wfT    = (bf16_t*)B;                    // wiT [3072,1536] / woT [1536,3072]
    bf16_t* sepb   = (bf16_t*)C_;                   // [8192,768]
    float*  mpart  = (float*)C_;                    // [8,32,1536] f32
    bf16_t* ctxcat = (bf16_t*)D;                    // [8192,1536]
    bf16_t* attn   = (bf16_t*)D;                    // [8192,1536]
    bf16_t* ebuf   = (bf16_t*)E;                    // [8192,1536]
    bf16_t* y2     = (bf16_t*)E;                    // [8192,1536]
    bf16_t* wT     = (bf16_t*)F;
    int*    flag   = (int*)XP;
    float*  pooled = (float*)(XP + 256);            // [8,1536] f32
    bf16_t* cbias  = (bf16_t*)(XP + 256 + 49152);   // [3072]

    dim3 blk(256);

    auto gemm = [&](const bf16_t* Ai, const bf16_t* Bt, bf16_t* Ci, const void* bias,
                    long long biasOff, const bf16_t* emul, int lde, const int* fl,
                    int M, int N, int Kd, int lda, int ldb, int ldc,
                    float scale, int act, int beta, int nlim) {
        dim3 g(M / 128, (N + 127) / 128, 1);
        gemm_tile<<<g, blk, 0, stream>>>(Ai, Bt, Ci, bias, biasOff, emul, lde, fl,
                                         M, N, Kd, lda, ldb, ldc,
                                         scale, act, beta, nlim);
    };
    auto transpose = [&](const void* in, bf16_t* out, int R, int Cc, int Cpad, int ldin,
                         long long inOff, int batch, long long sInB, long long sOutB,
                         const int* fl) {
        dim3 g(Cpad / 32, R / 32, batch);
        transpose_pad<<<g, blk, 0, stream>>>(in, out, R, Cc, ldin, inOff, sInB, sOutB, fl);
    };

    // --- dtype probe + embed conversion ---
    detect_kernel<<<dim3(1), blk, 0, stream>>>(embed, flag);
    convert_embed<<<dim3(6144), blk, 0, stream>>>(embed, ebuf, flag);

    // --- merged Q|K|V|co projection: [8192,1536] x [3072,1536]^T -> [8192,3072] ---
    transpose(wq,  wT_all + 0ll * 768 * 1536, 1536, 768, 768, 768, 0, 1, 0, 0, flag);
    transpose(wk,  wT_all + 1ll * 768 * 1536, 1536, 768, 768, 768, 0, 1, 0, 0, flag);
    transpose(wv,  wT_all + 2ll * 768 * 1536, 1536, 768, 768, 768, 0, 1, 0, 0, flag);
    transpose(wco, wT_all + 3ll * 768 * 1536, 1536, 768, 768, 768, 0, 1, 0, 0, flag);
    concat_bias<<<dim3(12), blk, 0, stream>>>(bq, bk, bv, bco, cbias, flag);
    gemm(ebuf, wT_all, qkvco, cbias, 0, nullptr, 0, nullptr,
         8192, 3072, 1536, HH, HH, 3072, 1.0f, 0, 0, 3071);

    // --- separable conv: depthwise, then pointwise fused with *q ---
    dconv_kernel<<<dim3((BB * SS * HH) / 256), blk, 0, stream>>>(ebuf, dw, dconvb, flag);
    transpose(pw, wT, 1536, 768, 768, 768, 0, 1, 0, 0, flag);
    gemm(dconvb, wT, sepb, sep_b, 0, qkvco, 3072, flag,
         8192, 768, 1536, HH, HH, AHH, 1.0f, 0, 0, 767);

    // --- span conv kernels (wckT padded to 128 rows) ---
    transpose(wck, wT, 768, 56, 128, 56, 0, 1, 0, 0, flag);
    gemm(sepb, wT, ckb, bck, 0, nullptr, 0, flag,
         8192, 56, 768, AHH, AHH, 64, 1.0f, 0, 0, 127);
    ck_softmax<<<dim3((BB * SS * NHH) / 256), blk, 0, stream>>>(ckb, ckp);
    conv_out_kernel<<<dim3((BB * SS * AHH) / 256), blk, 0, stream>>>(qkvco + 2304, 3072, ckp, ctxcat);

    // --- fused flash attention (XCD-local grid: bh fastest) ---
    transpose(qkvco, vT, 1024, 768, 768, 3072, 1536, 8, 1024ll * 3072, 768ll * 1024, nullptr);
    flash_attn<<<dim3(64, 8), blk, 0, stream>>>(qkvco, vT, ctxcat);

    // --- self output + LN1 ---
    transpose(wso, wT, 1536, 1536, 1536, 1536, 0, 1, 0, 0, flag);
    gemm(ctxcat, wT, ybuf, bso, 0, nullptr, 0, flag,
         8192, 1536, 1536, HH, HH, HH, 1.0f, 0, 0, 1535);
    ln_kernel<<<dim3(8192), blk, 0, stream>>>(ybuf, ebuf, ln1g, ln1b, attn, flag);

    // --- FFN full-width + LN2 ---
    transpose(wi, wfT, 1536, 3072, 3072, 3072, 0, 1, 0, 0, flag);      // wiT [3072,1536]
    gemm(attn, wfT, interb, bi, 0, nullptr, 0, flag,
         8192, 3072, 1536, HH, HH, IMM, 1.0f, 1, 0, 3071);
    transpose(wo, wfT, 3072, 1536, 1536, 1536, 0, 1, 0, 0, flag);      // woT [1536,3072]
    gemm(interb, wfT, y2, bo, 0, nullptr, 0, flag,
         8192, 1536, 3072, IMM, IMM, HH, 1.0f, 0, 0, 1535);
    ln_kernel<<<dim3(8192), blk, 0, stream>>>(y2, attn, ln2g, ln2b, lout, flag);

    // --- pool + decode (partials in dead sepb slot) ---
    maxpool_p1<<<dim3(32, 8), blk, 0, stream>>>(lout, mpart);
    maxpool_p2<<<dim3(48), blk, 0, stream>>>(mpart, pooled);
    decoder_kernel<<<dim3(BB), blk, 0, stream>>>(pooled, wd, bd, d_out, flag);
}